// Round 1
// 380.110 us; speedup vs baseline: 1.0348x; 1.0348x over previous
//
#include <hip/hip_runtime.h>
#include <math.h>

typedef __bf16 bf16x8v __attribute__((ext_vector_type(8)));
typedef short bf16x4s __attribute__((ext_vector_type(4)));
typedef float f32x4 __attribute__((ext_vector_type(4)));

__device__ __forceinline__ void async_copy16(void* lds, const void* g) {
  __builtin_amdgcn_global_load_lds(
      (const __attribute__((address_space(1))) void*)g,
      (__attribute__((address_space(3))) void*)lds, 16, 0, 0);
}

// ---- f32 -> bf16 cast, all 7 tensors in one launch ----
struct CastArgs {
  const float* s[7];
  __bf16* d[7];
};
__global__ __launch_bounds__(256) void cast_kernel(CastArgs a) {
  const int t = blockIdx.y;
  const int n = (t < 3) ? 8388608 : 1048576;
  const int i = (blockIdx.x * 256 + threadIdx.x) * 8;
  if (i >= n) return;
  const float4 v0 = *(const float4*)(a.s[t] + i);
  const float4 v1 = *(const float4*)(a.s[t] + i + 4);
  bf16x8v o;
  o[0] = (__bf16)v0.x; o[1] = (__bf16)v0.y; o[2] = (__bf16)v0.z; o[3] = (__bf16)v0.w;
  o[4] = (__bf16)v1.x; o[5] = (__bf16)v1.y; o[6] = (__bf16)v1.z; o[7] = (__bf16)v1.w;
  *(bf16x8v*)(a.d[t] + i) = o;
}

// C[m,n] = sum_k A[m,k] * B[n,k]   (A: MxK row-major, B: NxK row-major, bf16)
// LDS tiles XOR-swizzled at 16B-block granularity (see round-3 notes).
// XCD locality: blocks are round-robined to the 8 XCDs by linear block id.
// For MODE 0/1 the LARGE operand is A (8192xK, indexed by bm) -> bm must
// determine the XCD: grid (bm=64, bn=8[, z]) gives linear%8 = bm%8, so all 8
// bn-blocks sharing an A row-block land on ONE XCD (A fetched once from HBM,
// was 8x = 134 MB/GEMM in r6). MODE 3's large operand is B (indexed by bn =
// blockIdx.x, grid (64,8)) -- already the good orientation.
// blockIdx.z selects the (A2,B2,C2) set (batched Q+K projections).
// MODE 0: C[row*N+col] (float, final output)
// MODE 1: split heads -> [B,H,S,dk]  (row=b*2048+s, col=h*64+d)
// MODE 3: V^T heads -> [B,H,dk,S]    (row=h*64+d [M=1024], col=b*2048+s [N=8192])
template <int MODE, typename OutT>
__global__ __launch_bounds__(256) void gemm_bt(const __bf16* A, const __bf16* B,
                                               OutT* C,
                                               const __bf16* A2, const __bf16* B2,
                                               OutT* C2,
                                               int M, int N, int K) {
  __shared__ __bf16 As[128 * 64];
  __shared__ __bf16 Bs[128 * 64];
  if (blockIdx.z == 1) { A = A2; B = B2; C = C2; }
  const int tid = threadIdx.x;
  const int wave = tid >> 6, lane = tid & 63;
  const int lgrp = lane >> 4, lmod = lane & 15;
  const int bm = (MODE == 3 ? blockIdx.y : blockIdx.x) * 128;
  const int bn = (MODE == 3 ? blockIdx.x : blockIdx.y) * 128;
  const int wm = (wave >> 1) * 64, wn = (wave & 1) * 64;

  f32x4 acc[4][4];
#pragma unroll
  for (int mi = 0; mi < 4; mi++)
#pragma unroll
    for (int ni = 0; ni < 4; ni++)
#pragma unroll
      for (int r = 0; r < 4; r++) acc[mi][ni][r] = 0.f;

  for (int kt = 0; kt < K; kt += 64) {
#pragma unroll
    for (int i = 0; i < 4; i++) {
      const int s = i * 256 + tid;      // 16B-block slot in 128x8-block tile
      const int r = s >> 3, cb = s & 7;
      const int gc = (cb ^ (r & 7)) * 8;  // swizzled global column (elements)
      async_copy16(&As[s * 8], &A[(size_t)(bm + r) * K + kt + gc]);
      async_copy16(&Bs[s * 8], &B[(size_t)(bn + r) * K + kt + gc]);
    }
    __syncthreads();
#pragma unroll
    for (int ks = 0; ks < 2; ks++) {
      bf16x8v af[4], bf[4];
#pragma unroll
      for (int mi = 0; mi < 4; mi++) {
        const int row = wm + mi * 16 + lmod;
        af[mi] = *(const bf16x8v*)&As[row * 64 + ((ks * 4 + lgrp) ^ (row & 7)) * 8];
      }
#pragma unroll
      for (int ni = 0; ni < 4; ni++) {
        const int row = wn + ni * 16 + lmod;
        bf[ni] = *(const bf16x8v*)&Bs[row * 64 + ((ks * 4 + lgrp) ^ (row & 7)) * 8];
      }
#pragma unroll
      for (int mi = 0; mi < 4; mi++)
#pragma unroll
        for (int ni = 0; ni < 4; ni++)
          acc[mi][ni] = __builtin_amdgcn_mfma_f32_16x16x32_bf16(af[mi], bf[ni],
                                                                acc[mi][ni], 0, 0, 0);
    }
    __syncthreads();
  }

#pragma unroll
  for (int mi = 0; mi < 4; mi++)
#pragma unroll
    for (int ni = 0; ni < 4; ni++)
#pragma unroll
      for (int r = 0; r < 4; r++) {
        const int row = bm + wm + mi * 16 + lgrp * 4 + r;
        const int col = bn + wn + ni * 16 + lmod;
        if (MODE == 0) {
          C[(size_t)row * N + col] = (OutT)acc[mi][ni][r];
        } else if (MODE == 1) {
          C[(size_t)(row >> 11) * 2097152 + (size_t)(col >> 6) * 131072 +
            (size_t)(row & 2047) * 64 + (col & 63)] = (OutT)acc[mi][ni][r];
        } else {  // MODE 3: Vt[b][h][d][s], row=h*64+d, col=b*2048+s (coalesced in s)
          C[(size_t)(col >> 11) * 2097152 + (size_t)(row >> 6) * 131072 +
            (size_t)(row & 63) * 2048 + (col & 2047)] = (OutT)acc[mi][ni][r];
        }
      }
}

// Flash attention, S^T formulation (P never touches LDS).
// Qh,Kh: [B,H,S,dk]; Vt: [B,H,dk,S]; O: [B,S,H*dk]  (all bf16)
// grid: (64 b*h, 16 q-tiles) -- y in blockIdx.x so linear%8 = y%8: all 16
// q-tile blocks sharing one head's K/V land on the same XCD (L2 reuse).
// block 256 (4 waves x 32 q-rows).
// S^T = K*Q^T via mfma(A=K, B=Q): C/D has q in lanes (col=lmod), kv in regs.
// kv processed in 64-wide sub-chunks (REAL loop, not unrolled) to halve the
// peak live set. NO min-waves launch-bounds clamp (r4/r5: (256,4) forced a
// 128-reg unified cap -> spill -> 1.2 GB scratch traffic).
// Round-7: defer-max (T13, THR=8 log2-units) skips the O-rescale + alpha
// broadcast when no q-row's max grew; l_run kept as per-lgrp PARTIAL sums
// (alpha is replica-uniform -> reduction legal to defer to epilogue);
// s_setprio(1) around MFMA clusters (T5, attn-regime +4-7%).
__global__ __launch_bounds__(256) void attn_kernel(const __bf16* __restrict__ Qh,
                                                   const __bf16* __restrict__ Kh,
                                                   const __bf16* __restrict__ Vt,
                                                   __bf16* __restrict__ O) {
  __shared__ __bf16 Ks[128 * 64];    // [kv][d], XOR-swizzled 16B blocks
  __shared__ __bf16 Vts[64 * 128];   // [d][kv], XOR-swizzled 16B blocks

  const int tid = threadIdx.x;
  const int wave = tid >> 6, lane = tid & 63;
  const int lgrp = lane >> 4, lmod = lane & 15;
  const int qt = blockIdx.y, y = blockIdx.x;  // y = b*16+h
  const size_t hb = (size_t)y * 131072;
  const __bf16* Qb = Qh + hb + (size_t)qt * 128 * 64;
  const __bf16* Kb = Kh + hb;
  const __bf16* Vb = Vt + hb;
  const int wq0 = wave * 32;

  // Q fragments (B-operand: n=q=lmod, k=d), pre-scaled by 0.125*log2(e)
  const float qscale = 0.125f * 1.44269504f;
  bf16x8v qf[2][2];  // [qtile][ks]
#pragma unroll
  for (int qi = 0; qi < 2; qi++)
#pragma unroll
    for (int ks = 0; ks < 2; ks++) {
      bf16x8v q = *(const bf16x8v*)&Qb[(wq0 + qi * 16 + lmod) * 64 + ks * 32 + lgrp * 8];
#pragma unroll
      for (int j = 0; j < 8; j++) q[j] = (__bf16)((float)q[j] * qscale);
      qf[qi][ks] = q;
    }

  // softmax state for q = wq0 + qi*16 + lmod (per-lane; l_run is a per-lgrp
  // PARTIAL sum, reduced across lgrp replicas only in the epilogue)
  float m_run[2] = {-INFINITY, -INFINITY};
  float l_run[2] = {0.f, 0.f};
  f32x4 oacc[2][4];  // [qtile][dtile]; col=d=lmod, row=q=lgrp*4+r
#pragma unroll
  for (int qi = 0; qi < 2; qi++)
#pragma unroll
    for (int nd = 0; nd < 4; nd++)
#pragma unroll
      for (int r = 0; r < 4; r++) oacc[qi][nd][r] = 0.f;

  for (int kv0 = 0; kv0 < 2048; kv0 += 128) {
#pragma unroll
    for (int i = 0; i < 4; i++) {
      const int s = i * 256 + tid;
      {  // Ks: 128 rows x 8 blocks
        const int r = s >> 3, cb = s & 7;
        async_copy16(&Ks[s * 8], &Kb[(size_t)(kv0 + r) * 64 + (cb ^ (r & 7)) * 8]);
      }
      {  // Vts: 64 rows x 16 blocks
        const int r = s >> 4, cb = s & 15;
        async_copy16(&Vts[s * 8], &Vb[(size_t)r * 2048 + kv0 + (cb ^ (r & 7)) * 8]);
      }
    }
    __syncthreads();

#pragma unroll 1  // keep halves SEPARATE: merging doubles live registers
    for (int half = 0; half < 2; half++) {
      // S^T = K Q^T over 64 kv: st[kvtile][qtile], col=q=lmod, row=kv
      f32x4 st[4][2];
#pragma unroll
      for (int t = 0; t < 4; t++)
#pragma unroll
        for (int qi = 0; qi < 2; qi++)
#pragma unroll
          for (int r = 0; r < 4; r++) st[t][qi][r] = 0.f;
#pragma unroll
      for (int ks = 0; ks < 2; ks++) {
#pragma unroll
        for (int t = 0; t < 4; t++) {
          const int row = half * 64 + t * 16 + lmod;
          const bf16x8v kf =
              *(const bf16x8v*)&Ks[row * 64 + ((ks * 4 + lgrp) ^ (row & 7)) * 8];
          __builtin_amdgcn_s_setprio(1);
#pragma unroll
          for (int qi = 0; qi < 2; qi++)
            st[t][qi] = __builtin_amdgcn_mfma_f32_16x16x32_bf16(kf, qf[qi][ks],
                                                                st[t][qi], 0, 0, 0);
          __builtin_amdgcn_s_setprio(0);
        }
      }

      // tile max (tree reduce, depth 4 instead of 15-deep serial chain)
      float rmax_l[2];
#pragma unroll
      for (int qi = 0; qi < 2; qi++) {
        float tm[4];
#pragma unroll
        for (int t = 0; t < 4; t++)
          tm[t] = fmaxf(fmaxf(st[t][qi][0], st[t][qi][1]),
                        fmaxf(st[t][qi][2], st[t][qi][3]));
        float rmax = fmaxf(fmaxf(tm[0], tm[1]), fmaxf(tm[2], tm[3]));
        rmax = fmaxf(rmax, __shfl_xor(rmax, 16));
        rmax = fmaxf(rmax, __shfl_xor(rmax, 32));
        rmax_l[qi] = rmax;
      }
      // defer-max: only rescale when some q-row's max grew by >8 (log2 units;
      // P then bounded by 2^8, fine in bf16/f32, output is a p-ratio).
      // First chunk: m_run = -inf -> condition false -> rescale path taken
      // (alpha = exp2(-inf) = 0, oacc/l_run already 0).
      if (!__all(rmax_l[0] - m_run[0] <= 8.f && rmax_l[1] - m_run[1] <= 8.f)) {
        float alpha_l[2];
#pragma unroll
        for (int qi = 0; qi < 2; qi++) {
          const float mnew = fmaxf(m_run[qi], rmax_l[qi]);
          alpha_l[qi] = __builtin_amdgcn_exp2f(m_run[qi] - mnew);
          m_run[qi] = mnew;
          l_run[qi] *= alpha_l[qi];  // partial sum scales uniformly
        }
        // broadcast alpha from stat-lanes (lmod=q) to O-rows (q=lgrp*4+r)
#pragma unroll
        for (int qi = 0; qi < 2; qi++)
#pragma unroll
          for (int r = 0; r < 4; r++) {
            const float ar = __shfl(alpha_l[qi], lgrp * 4 + r);
#pragma unroll
            for (int nd = 0; nd < 4; nd++) oacc[qi][nd][r] *= ar;
          }
      }

      // PV: exp2 on the fly; P^T fragment feeds mfma_16x16x16 A-operand directly
      float psum[2] = {0.f, 0.f};
#pragma unroll
      for (int t = 0; t < 4; t++) {
        bf16x4s vf[4];  // B-operand: n=d=lmod, k=kv
        const int kvb = half * 64 + t * 16 + lgrp * 4;
#pragma unroll
        for (int nd = 0; nd < 4; nd++) {
          const int row = nd * 16 + lmod;
          vf[nd] =
              *(const bf16x4s*)&Vts[row * 128 + ((kvb >> 3) ^ (row & 7)) * 8 + (kvb & 7)];
        }
#pragma unroll
        for (int qi = 0; qi < 2; qi++) {
          union { __bf16 b[4]; bf16x4s s; } pf;
#pragma unroll
          for (int r = 0; r < 4; r++) {
            const float p = __builtin_amdgcn_exp2f(st[t][qi][r] - m_run[qi]);
            psum[qi] += p;
            pf.b[r] = (__bf16)p;
          }
          __builtin_amdgcn_s_setprio(1);
#pragma unroll
          for (int nd = 0; nd < 4; nd++)
            oacc[qi][nd] = __builtin_amdgcn_mfma_f32_16x16x16bf16_1k(pf.s, vf[nd],
                                                                     oacc[qi][nd], 0, 0, 0);
          __builtin_amdgcn_s_setprio(0);
        }
      }
      l_run[0] += psum[0];  // per-lgrp partial; no cross-lane reduce here
      l_run[1] += psum[1];
    }
    __syncthreads();  // protect Ks/Vts before next stage
  }

  const int b = y >> 4, h = y & 15;
#pragma unroll
  for (int qi = 0; qi < 2; qi++) {
    // reduce the per-lgrp partial l across the 4 replicas (lanes 16 apart)
    float l = l_run[qi];
    l += __shfl_xor(l, 16);
    l += __shfl_xor(l, 32);
    const float linv = 1.f / l;
#pragma unroll
    for (int r = 0; r < 4; r++) {
      const float inv = __shfl(linv, lgrp * 4 + r);
      const int srow = qt * 128 + wq0 + qi * 16 + lgrp * 4 + r;
      const size_t base = ((size_t)(b * 2048 + srow)) * 1024 + h * 64;
#pragma unroll
      for (int nd = 0; nd < 4; nd++)
        O[base + nd * 16 + lmod] = (__bf16)(oacc[qi][nd][r] * inv);
    }
  }
}

extern "C" void kernel_launch(void* const* d_in, const int* in_sizes, int n_in,
                              void* d_out, int out_size, void* d_ws, size_t ws_size,
                              hipStream_t stream) {
  const float* Qin = (const float*)d_in[0];
  const float* Kin = (const float*)d_in[1];
  const float* Vin = (const float*)d_in[2];
  const float* Wq = (const float*)d_in[3];
  const float* Wk = (const float*)d_in[4];
  const float* Wv = (const float*)d_in[5];
  const float* Wo = (const float*)d_in[6];
  float* out = (float*)d_out;

  __bf16* base = (__bf16*)d_ws;
  __bf16* Qbf = base;                    // 8388608
  __bf16* Kbf = base + 8388608;
  __bf16* Vbf = base + 16777216;
  __bf16* Wqb = base + 25165824;         // 1048576 each
  __bf16* Wkb = base + 26214400;
  __bf16* Wvb = base + 27262976;
  __bf16* Wob = base + 28311552;
  __bf16* Qh = base + 29360128;          // [B,H,S,dk]
  __bf16* Kh = base + 37748736;          // [B,H,S,dk]
  __bf16* Vt = base + 46137344;          // [B,H,dk,S]
  __bf16* AO = Qbf;                      // aliases Qbf (dead after gemm1)

  CastArgs ca;
  ca.s[0] = Qin; ca.s[1] = Kin; ca.s[2] = Vin;
  ca.s[3] = Wq;  ca.s[4] = Wk;  ca.s[5] = Wv;  ca.s[6] = Wo;
  ca.d[0] = Qbf; ca.d[1] = Kbf; ca.d[2] = Vbf;
  ca.d[3] = Wqb; ca.d[4] = Wkb; ca.d[5] = Wvb; ca.d[6] = Wob;
  cast_kernel<<<dim3(4096, 7), 256, 0, stream>>>(ca);

  const int M = 8192, N = 1024, K = 1024;
  dim3 bb(256);
  // Q and K projections batched: grid (bm=64, bn=8, z=2), XCD = bm%8
  gemm_bt<1, __bf16><<<dim3(64, 8, 2), bb, 0, stream>>>(Qbf, Wqb, Qh,
                                                        Kbf, Wkb, Kh, M, N, K);
  // V^T: swap operands -> Vt[n][s] = sum_k Wv[n][k] * Vin[s][k]  (M=1024, N=8192)
  // grid (bn=64, bm=8): XCD = bn%8, bn indexes the large operand (Vin) -- good.
  gemm_bt<3, __bf16><<<dim3(64, 8), bb, 0, stream>>>(Wvb, Vbf, Vt,
                                                     nullptr, nullptr, nullptr,
                                                     1024, 8192, K);
  attn_kernel<<<dim3(64, 16), bb, 0, stream>>>(Qh, Kh, Vt, AO);
  gemm_bt<0, float><<<dim3(64, 8), bb, 0, stream>>>(AO, Wob, out,
                                                    nullptr, nullptr, nullptr,
                                                    M, N, K);
}

// Round 2
// 376.638 us; speedup vs baseline: 1.0443x; 1.0092x over previous
//
#include <hip/hip_runtime.h>
#include <math.h>

typedef __bf16 bf16x8v __attribute__((ext_vector_type(8)));
typedef float f32x4 __attribute__((ext_vector_type(4)));
typedef float f32x16 __attribute__((ext_vector_type(16)));

__device__ __forceinline__ void async_copy16(void* lds, const void* g) {
  __builtin_amdgcn_global_load_lds(
      (const __attribute__((address_space(1))) void*)g,
      (__attribute__((address_space(3))) void*)lds, 16, 0, 0);
}

// ---- f32 -> bf16 cast, all 7 tensors in one launch ----
struct CastArgs {
  const float* s[7];
  __bf16* d[7];
};
__global__ __launch_bounds__(256) void cast_kernel(CastArgs a) {
  const int t = blockIdx.y;
  const int n = (t < 3) ? 8388608 : 1048576;
  const int i = (blockIdx.x * 256 + threadIdx.x) * 8;
  if (i >= n) return;
  const float4 v0 = *(const float4*)(a.s[t] + i);
  const float4 v1 = *(const float4*)(a.s[t] + i + 4);
  bf16x8v o;
  o[0] = (__bf16)v0.x; o[1] = (__bf16)v0.y; o[2] = (__bf16)v0.z; o[3] = (__bf16)v0.w;
  o[4] = (__bf16)v1.x; o[5] = (__bf16)v1.y; o[6] = (__bf16)v1.z; o[7] = (__bf16)v1.w;
  *(bf16x8v*)(a.d[t] + i) = o;
}

// C[m,n] = sum_k A[m,k] * B[n,k]   (A: MxK row-major, B: NxK row-major, bf16)
// LDS tiles XOR-swizzled at 16B-block granularity (see round-3 notes).
// XCD locality: blocks are round-robined to the 8 XCDs by linear block id.
// For MODE 0/1 the LARGE operand is A (8192xK, indexed by bm) -> bm must
// determine the XCD: grid (bm=64, bn=8[, z]) gives linear%8 = bm%8, so all 8
// bn-blocks sharing an A row-block land on ONE XCD (A fetched once from HBM,
// was 8x = 134 MB/GEMM in r6). MODE 3's large operand is B (indexed by bn =
// blockIdx.x, grid (64,8)) -- already the good orientation.
// blockIdx.z selects the (A2,B2,C2) set (batched Q+K projections).
// MODE 0: C[row*N+col] (float, final output)
// MODE 1: split heads -> [B,H,S,dk]  (row=b*2048+s, col=h*64+d)
// MODE 3: V^T heads -> [B,H,dk,S]    (row=h*64+d [M=1024], col=b*2048+s [N=8192])
template <int MODE, typename OutT>
__global__ __launch_bounds__(256) void gemm_bt(const __bf16* A, const __bf16* B,
                                               OutT* C,
                                               const __bf16* A2, const __bf16* B2,
                                               OutT* C2,
                                               int M, int N, int K) {
  __shared__ __bf16 As[128 * 64];
  __shared__ __bf16 Bs[128 * 64];
  if (blockIdx.z == 1) { A = A2; B = B2; C = C2; }
  const int tid = threadIdx.x;
  const int wave = tid >> 6, lane = tid & 63;
  const int lgrp = lane >> 4, lmod = lane & 15;
  const int bm = (MODE == 3 ? blockIdx.y : blockIdx.x) * 128;
  const int bn = (MODE == 3 ? blockIdx.x : blockIdx.y) * 128;
  const int wm = (wave >> 1) * 64, wn = (wave & 1) * 64;

  f32x4 acc[4][4];
#pragma unroll
  for (int mi = 0; mi < 4; mi++)
#pragma unroll
    for (int ni = 0; ni < 4; ni++)
#pragma unroll
      for (int r = 0; r < 4; r++) acc[mi][ni][r] = 0.f;

  for (int kt = 0; kt < K; kt += 64) {
#pragma unroll
    for (int i = 0; i < 4; i++) {
      const int s = i * 256 + tid;      // 16B-block slot in 128x8-block tile
      const int r = s >> 3, cb = s & 7;
      const int gc = (cb ^ (r & 7)) * 8;  // swizzled global column (elements)
      async_copy16(&As[s * 8], &A[(size_t)(bm + r) * K + kt + gc]);
      async_copy16(&Bs[s * 8], &B[(size_t)(bn + r) * K + kt + gc]);
    }
    __syncthreads();
#pragma unroll
    for (int ks = 0; ks < 2; ks++) {
      bf16x8v af[4], bf[4];
#pragma unroll
      for (int mi = 0; mi < 4; mi++) {
        const int row = wm + mi * 16 + lmod;
        af[mi] = *(const bf16x8v*)&As[row * 64 + ((ks * 4 + lgrp) ^ (row & 7)) * 8];
      }
#pragma unroll
      for (int ni = 0; ni < 4; ni++) {
        const int row = wn + ni * 16 + lmod;
        bf[ni] = *(const bf16x8v*)&Bs[row * 64 + ((ks * 4 + lgrp) ^ (row & 7)) * 8];
      }
#pragma unroll
      for (int mi = 0; mi < 4; mi++)
#pragma unroll
        for (int ni = 0; ni < 4; ni++)
          acc[mi][ni] = __builtin_amdgcn_mfma_f32_16x16x32_bf16(af[mi], bf[ni],
                                                                acc[mi][ni], 0, 0, 0);
    }
    __syncthreads();
  }

#pragma unroll
  for (int mi = 0; mi < 4; mi++)
#pragma unroll
    for (int ni = 0; ni < 4; ni++)
#pragma unroll
      for (int r = 0; r < 4; r++) {
        const int row = bm + wm + mi * 16 + lgrp * 4 + r;
        const int col = bn + wn + ni * 16 + lmod;
        if (MODE == 0) {
          C[(size_t)row * N + col] = (OutT)acc[mi][ni][r];
        } else if (MODE == 1) {
          C[(size_t)(row >> 11) * 2097152 + (size_t)(col >> 6) * 131072 +
            (size_t)(row & 2047) * 64 + (col & 63)] = (OutT)acc[mi][ni][r];
        } else {  // MODE 3: Vt[b][h][d][s], row=h*64+d, col=b*2048+s (coalesced in s)
          C[(size_t)(col >> 11) * 2097152 + (size_t)(row >> 6) * 131072 +
            (size_t)(row & 63) * 2048 + (col & 2047)] = (OutT)acc[mi][ni][r];
        }
      }
}

// Flash attention, S^T formulation (P never touches LDS), 32x32 MFMA form.
// Qh,Kh: [B,H,S,dk]; Vt: [B,H,dk,S]; O: [B,S,H*dk]  (all bf16)
// grid: (64 b*h, 16 q-tiles); block 256 (4 waves x 32 q-rows).
// Round-8: both QK^T and PV use full-rate mfma_f32_32x32x16_bf16 (PV was the
// half-rate legacy 16x16x16_1k). S^T = K*Q^T: C col = q = lane&31, row(reg) =
// (reg&3)+8*(reg>>2)+4*hi -- ONE q per lane => softmax stats fully lane-local
// (no shfl broadcasts in steady path). P(f32, per-reg) -> PV A-fragment
// (row=q=lane&31, k=hi*8+j) via the T12 recipe: v_cvt_pk_bf16_f32 pairs +
// v_permlane32_swap_b32 ({w0,w2}=swap(pk(r0,r1),pk(r4,r5)),
// {w1,w3}=swap(pk(r2,r3),pk(r6,r7)) -- verified reg-by-reg vs layouts).
// Defer-max (THR=8 log2) keeps the rescale path rare; l_run per-hi partial,
// reduced once in epilogue.
__global__ __launch_bounds__(256) void attn_kernel(const __bf16* __restrict__ Qh,
                                                   const __bf16* __restrict__ Kh,
                                                   const __bf16* __restrict__ Vt,
                                                   __bf16* __restrict__ O) {
  __shared__ __bf16 Ks[128 * 64];    // [kv][d], XOR-swizzled 16B blocks
  __shared__ __bf16 Vts[64 * 128];   // [d][kv], XOR-swizzled 16B blocks

  const int tid = threadIdx.x;
  const int wave = tid >> 6, lane = tid & 63;
  const int l31 = lane & 31, hi = lane >> 5;
  const int qt = blockIdx.y, y = blockIdx.x;  // y = b*16+h
  const size_t hb = (size_t)y * 131072;
  const __bf16* Qb = Qh + hb + (size_t)qt * 128 * 64;
  const __bf16* Kb = Kh + hb;
  const __bf16* Vb = Vt + hb;
  const int wq0 = wave * 32;

  // Q fragments (B-operand of 32x32x16: col=q=lane&31, k=d=hi*8+j),
  // pre-scaled by 0.125*log2(e). 4 d-ksteps of 16.
  const float qscale = 0.125f * 1.44269504f;
  bf16x8v qf[4];
#pragma unroll
  for (int ks = 0; ks < 4; ks++) {
    bf16x8v q = *(const bf16x8v*)&Qb[(wq0 + l31) * 64 + ks * 16 + hi * 8];
#pragma unroll
    for (int j = 0; j < 8; j++) q[j] = (__bf16)((float)q[j] * qscale);
    qf[ks] = q;
  }

  // softmax state for q = wq0 + l31 (lane-local; l_run is a per-hi PARTIAL sum)
  float m_run = -INFINITY;
  float l_run = 0.f;
  f32x16 oacc[2];  // [d-tile]; col=d=nd*32+l31, row(reg)=(reg&3)+8*(reg>>2)+4*hi
#pragma unroll
  for (int nd = 0; nd < 2; nd++)
#pragma unroll
    for (int r = 0; r < 16; r++) oacc[nd][r] = 0.f;

  for (int kv0 = 0; kv0 < 2048; kv0 += 128) {
#pragma unroll
    for (int i = 0; i < 4; i++) {
      const int s = i * 256 + tid;
      {  // Ks: 128 rows x 8 blocks
        const int r = s >> 3, cb = s & 7;
        async_copy16(&Ks[s * 8], &Kb[(size_t)(kv0 + r) * 64 + (cb ^ (r & 7)) * 8]);
      }
      {  // Vts: 64 rows x 16 blocks
        const int r = s >> 4, cb = s & 15;
        async_copy16(&Vts[s * 8], &Vb[(size_t)r * 2048 + kv0 + (cb ^ (r & 7)) * 8]);
      }
    }
    __syncthreads();

#pragma unroll 1  // keep halves SEPARATE: merging doubles live registers
    for (int half = 0; half < 2; half++) {
      // S^T = K Q^T over 64 kv: st[kvt] (kv tile of 32), col=q=lane&31,
      // row = kvt*32 + (reg&3)+8*(reg>>2)+4*hi
      f32x16 st[2];
#pragma unroll
      for (int kvt = 0; kvt < 2; kvt++)
#pragma unroll
        for (int r = 0; r < 16; r++) st[kvt][r] = 0.f;
#pragma unroll
      for (int ks = 0; ks < 4; ks++) {
        const int sl = ((ks * 2 + hi) ^ (l31 & 7)) * 8;
        const bf16x8v kf0 =
            *(const bf16x8v*)&Ks[(half * 64 + l31) * 64 + sl];
        const bf16x8v kf1 =
            *(const bf16x8v*)&Ks[(half * 64 + 32 + l31) * 64 + sl];
        __builtin_amdgcn_s_setprio(1);
        st[0] = __builtin_amdgcn_mfma_f32_32x32x16_bf16(kf0, qf[ks], st[0], 0, 0, 0);
        st[1] = __builtin_amdgcn_mfma_f32_32x32x16_bf16(kf1, qf[ks], st[1], 0, 0, 0);
        __builtin_amdgcn_s_setprio(0);
      }

      // row max over own 32 st values (tree, depth 5) + cross-hi swap
      float b[16];
#pragma unroll
      for (int j = 0; j < 16; j++) b[j] = fmaxf(st[0][j], st[1][j]);
#pragma unroll
      for (int s = 8; s > 0; s >>= 1)
#pragma unroll
        for (int j = 0; j < 8; j++)
          if (j < s) b[j] = fmaxf(b[j], b[j + s]);
      float rmax = b[0];
      rmax = fmaxf(rmax, __shfl_xor(rmax, 32));

      // defer-max: rescale only when some q-row's max grew by >8 (log2 units).
      // First chunk: m_run=-inf -> fires -> alpha=exp2(-inf)=0, state is 0.
      if (!__all(rmax - m_run <= 8.f)) {
        const float mnew = fmaxf(m_run, rmax);
        const float alpha = __builtin_amdgcn_exp2f(m_run - mnew);
        m_run = mnew;
        l_run *= alpha;  // partial sum scales uniformly
#pragma unroll
        for (int r = 0; r < 16; r++) {
          const float ar = __shfl(alpha, (r & 3) + 8 * (r >> 2) + 4 * hi);
          oacc[0][r] *= ar;
          oacc[1][r] *= ar;
        }
      }

      // PV: exp2 on the fly; P -> bf16 A-fragments via cvt_pk + permlane32_swap.
      float psum = 0.f;
#pragma unroll
      for (int kvt = 0; kvt < 2; kvt++) {
#pragma unroll
        for (int sub = 0; sub < 2; sub++) {
          const int ks2 = kvt * 2 + sub;      // kv kstep of 16 within this half
          const int vs = ((half * 8 + ks2 * 2 + hi) ^ (l31 & 7)) * 8;
          const bf16x8v vf0 = *(const bf16x8v*)&Vts[l31 * 128 + vs];
          const bf16x8v vf1 = *(const bf16x8v*)&Vts[(32 + l31) * 128 + vs];
          const int o = sub * 8;
          float p[8];
#pragma unroll
          for (int j = 0; j < 8; j++) {
            p[j] = __builtin_amdgcn_exp2f(st[kvt][o + j] - m_run);
            psum += p[j];
          }
          unsigned x0, y0, x1, y1;
          asm("v_cvt_pk_bf16_f32 %0, %1, %2" : "=v"(x0) : "v"(p[0]), "v"(p[1]));
          asm("v_cvt_pk_bf16_f32 %0, %1, %2" : "=v"(y0) : "v"(p[4]), "v"(p[5]));
          asm("v_cvt_pk_bf16_f32 %0, %1, %2" : "=v"(x1) : "v"(p[2]), "v"(p[3]));
          asm("v_cvt_pk_bf16_f32 %0, %1, %2" : "=v"(y1) : "v"(p[6]), "v"(p[7]));
          // {w0,w2} = swap(x0,y0); {w1,w3} = swap(x1,y1)
          asm("v_permlane32_swap_b32 %0, %1" : "+v"(x0), "+v"(y0));
          asm("v_permlane32_swap_b32 %0, %1" : "+v"(x1), "+v"(y1));
          union { unsigned u[4]; bf16x8v v; } af;
          af.u[0] = x0; af.u[1] = x1; af.u[2] = y0; af.u[3] = y1;
          __builtin_amdgcn_s_setprio(1);
          oacc[0] = __builtin_amdgcn_mfma_f32_32x32x16_bf16(af.v, vf0, oacc[0], 0, 0, 0);
          oacc[1] = __builtin_amdgcn_mfma_f32_32x32x16_bf16(af.v, vf1, oacc[1], 0, 0, 0);
          __builtin_amdgcn_s_setprio(0);
        }
      }
      l_run += psum;  // per-hi partial; reduced in epilogue
    }
    __syncthreads();  // protect Ks/Vts before next stage
  }

  // epilogue: reduce l across the 2 hi replicas, broadcast 1/l to O-rows
  l_run += __shfl_xor(l_run, 32);
  const float linv = 1.f / l_run;
  const int b = y >> 4, h = y & 15;
#pragma unroll
  for (int r = 0; r < 16; r++) {
    const int q = (r & 3) + 8 * (r >> 2) + 4 * hi;
    const float inv = __shfl(linv, q);
    const int srow = qt * 128 + wq0 + q;
    const size_t base = ((size_t)(b * 2048 + srow)) * 1024 + h * 64;
    O[base + l31] = (__bf16)(oacc[0][r] * inv);
    O[base + 32 + l31] = (__bf16)(oacc[1][r] * inv);
  }
}

extern "C" void kernel_launch(void* const* d_in, const int* in_sizes, int n_in,
                              void* d_out, int out_size, void* d_ws, size_t ws_size,
                              hipStream_t stream) {
  const float* Qin = (const float*)d_in[0];
  const float* Kin = (const float*)d_in[1];
  const float* Vin = (const float*)d_in[2];
  const float* Wq = (const float*)d_in[3];
  const float* Wk = (const float*)d_in[4];
  const float* Wv = (const float*)d_in[5];
  const float* Wo = (const float*)d_in[6];
  float* out = (float*)d_out;

  __bf16* base = (__bf16*)d_ws;
  __bf16* Qbf = base;                    // 8388608
  __bf16* Kbf = base + 8388608;
  __bf16* Vbf = base + 16777216;
  __bf16* Wqb = base + 25165824;         // 1048576 each
  __bf16* Wkb = base + 26214400;
  __bf16* Wvb = base + 27262976;
  __bf16* Wob = base + 28311552;
  __bf16* Qh = base + 29360128;          // [B,H,S,dk]
  __bf16* Kh = base + 37748736;          // [B,H,S,dk]
  __bf16* Vt = base + 46137344;          // [B,H,dk,S]
  __bf16* AO = Qbf;                      // aliases Qbf (dead after gemm1)

  CastArgs ca;
  ca.s[0] = Qin; ca.s[1] = Kin; ca.s[2] = Vin;
  ca.s[3] = Wq;  ca.s[4] = Wk;  ca.s[5] = Wv;  ca.s[6] = Wo;
  ca.d[0] = Qbf; ca.d[1] = Kbf; ca.d[2] = Vbf;
  ca.d[3] = Wqb; ca.d[4] = Wkb; ca.d[5] = Wvb; ca.d[6] = Wob;
  cast_kernel<<<dim3(4096, 7), 256, 0, stream>>>(ca);

  const int M = 8192, N = 1024, K = 1024;
  dim3 bb(256);
  // Q and K projections batched: grid (bm=64, bn=8, z=2), XCD = bm%8
  gemm_bt<1, __bf16><<<dim3(64, 8, 2), bb, 0, stream>>>(Qbf, Wqb, Qh,
                                                        Kbf, Wkb, Kh, M, N, K);
  // V^T: swap operands -> Vt[n][s] = sum_k Wv[n][k] * Vin[s][k]  (M=1024, N=8192)
  // grid (bn=64, bm=8): XCD = bn%8, bn indexes the large operand (Vin) -- good.
  gemm_bt<3, __bf16><<<dim3(64, 8), bb, 0, stream>>>(Wvb, Vbf, Vt,
                                                     nullptr, nullptr, nullptr,
                                                     1024, 8192, K);
  attn_kernel<<<dim3(64, 16), bb, 0, stream>>>(Qh, Kh, Vt, AO);
  gemm_bt<0, float><<<dim3(64, 8), bb, 0, stream>>>(AO, Wob, out,
                                                    nullptr, nullptr, nullptr,
                                                    M, N, K);
}

// Round 3
// 370.616 us; speedup vs baseline: 1.0613x; 1.0162x over previous
//
#include <hip/hip_runtime.h>
#include <math.h>

typedef __bf16 bf16x8v __attribute__((ext_vector_type(8)));
typedef float f32x4 __attribute__((ext_vector_type(4)));
typedef float f32x16 __attribute__((ext_vector_type(16)));

__device__ __forceinline__ void async_copy16(void* lds, const void* g) {
  __builtin_amdgcn_global_load_lds(
      (const __attribute__((address_space(1))) void*)g,
      (__attribute__((address_space(3))) void*)lds, 16, 0, 0);
}

// ---- f32 -> bf16 cast, all 7 tensors in one launch ----
struct CastArgs {
  const float* s[7];
  __bf16* d[7];
};
__global__ __launch_bounds__(256) void cast_kernel(CastArgs a) {
  const int t = blockIdx.y;
  const int n = (t < 3) ? 8388608 : 1048576;
  const int i = (blockIdx.x * 256 + threadIdx.x) * 8;
  if (i >= n) return;
  const float4 v0 = *(const float4*)(a.s[t] + i);
  const float4 v1 = *(const float4*)(a.s[t] + i + 4);
  bf16x8v o;
  o[0] = (__bf16)v0.x; o[1] = (__bf16)v0.y; o[2] = (__bf16)v0.z; o[3] = (__bf16)v0.w;
  o[4] = (__bf16)v1.x; o[5] = (__bf16)v1.y; o[6] = (__bf16)v1.z; o[7] = (__bf16)v1.w;
  *(bf16x8v*)(a.d[t] + i) = o;
}

// C[m,n] = sum_k A[m,k] * B[n,k]   (A: MxK row-major, B: NxK row-major, bf16)
// LDS tiles XOR-swizzled at 16B-block granularity (see round-3 notes).
// XCD locality: blocks are round-robined to the 8 XCDs by linear block id.
// For MODE 0/1 the LARGE operand is A (8192xK, indexed by bm) -> bm must
// determine the XCD: grid (bm=64, bn=8[, z]) gives linear%8 = bm%8, so all 8
// bn-blocks sharing an A row-block land on ONE XCD (A fetched once from HBM,
// was 8x = 134 MB/GEMM in r6). MODE 3's large operand is B (indexed by bn =
// blockIdx.x, grid (64,8)) -- already the good orientation.
// blockIdx.z selects the (A2,B2,C2) set (batched Q+K projections).
// MODE 0: C[row*N+col] (float, final output)
// MODE 1: split heads -> [B,H,S,dk]  (row=b*2048+s, col=h*64+d)
// MODE 3: V^T heads -> [B,H,dk,S]    (row=h*64+d [M=1024], col=b*2048+s [N=8192])
template <int MODE, typename OutT>
__global__ __launch_bounds__(256) void gemm_bt(const __bf16* A, const __bf16* B,
                                               OutT* C,
                                               const __bf16* A2, const __bf16* B2,
                                               OutT* C2,
                                               int M, int N, int K) {
  __shared__ __bf16 As[128 * 64];
  __shared__ __bf16 Bs[128 * 64];
  if (blockIdx.z == 1) { A = A2; B = B2; C = C2; }
  const int tid = threadIdx.x;
  const int wave = tid >> 6, lane = tid & 63;
  const int lgrp = lane >> 4, lmod = lane & 15;
  const int bm = (MODE == 3 ? blockIdx.y : blockIdx.x) * 128;
  const int bn = (MODE == 3 ? blockIdx.x : blockIdx.y) * 128;
  const int wm = (wave >> 1) * 64, wn = (wave & 1) * 64;

  f32x4 acc[4][4];
#pragma unroll
  for (int mi = 0; mi < 4; mi++)
#pragma unroll
    for (int ni = 0; ni < 4; ni++)
#pragma unroll
      for (int r = 0; r < 4; r++) acc[mi][ni][r] = 0.f;

  for (int kt = 0; kt < K; kt += 64) {
#pragma unroll
    for (int i = 0; i < 4; i++) {
      const int s = i * 256 + tid;      // 16B-block slot in 128x8-block tile
      const int r = s >> 3, cb = s & 7;
      const int gc = (cb ^ (r & 7)) * 8;  // swizzled global column (elements)
      async_copy16(&As[s * 8], &A[(size_t)(bm + r) * K + kt + gc]);
      async_copy16(&Bs[s * 8], &B[(size_t)(bn + r) * K + kt + gc]);
    }
    __syncthreads();
#pragma unroll
    for (int ks = 0; ks < 2; ks++) {
      bf16x8v af[4], bf[4];
#pragma unroll
      for (int mi = 0; mi < 4; mi++) {
        const int row = wm + mi * 16 + lmod;
        af[mi] = *(const bf16x8v*)&As[row * 64 + ((ks * 4 + lgrp) ^ (row & 7)) * 8];
      }
#pragma unroll
      for (int ni = 0; ni < 4; ni++) {
        const int row = wn + ni * 16 + lmod;
        bf[ni] = *(const bf16x8v*)&Bs[row * 64 + ((ks * 4 + lgrp) ^ (row & 7)) * 8];
      }
#pragma unroll
      for (int mi = 0; mi < 4; mi++)
#pragma unroll
        for (int ni = 0; ni < 4; ni++)
          acc[mi][ni] = __builtin_amdgcn_mfma_f32_16x16x32_bf16(af[mi], bf[ni],
                                                                acc[mi][ni], 0, 0, 0);
    }
    __syncthreads();
  }

#pragma unroll
  for (int mi = 0; mi < 4; mi++)
#pragma unroll
    for (int ni = 0; ni < 4; ni++)
#pragma unroll
      for (int r = 0; r < 4; r++) {
        const int row = bm + wm + mi * 16 + lgrp * 4 + r;
        const int col = bn + wn + ni * 16 + lmod;
        if (MODE == 0) {
          C[(size_t)row * N + col] = (OutT)acc[mi][ni][r];
        } else if (MODE == 1) {
          C[(size_t)(row >> 11) * 2097152 + (size_t)(col >> 6) * 131072 +
            (size_t)(row & 2047) * 64 + (col & 63)] = (OutT)acc[mi][ni][r];
        } else {  // MODE 3: Vt[b][h][d][s], row=h*64+d, col=b*2048+s (coalesced in s)
          C[(size_t)(col >> 11) * 2097152 + (size_t)(row >> 6) * 131072 +
            (size_t)(row & 63) * 2048 + (col & 2047)] = (OutT)acc[mi][ni][r];
        }
      }
}

// Flash attention, S^T formulation (P never touches LDS), 32x32 MFMA form.
// Qh,Kh: [B,H,S,dk]; Vt: [B,H,dk,S]; O: [B,S,H*dk]  (all bf16)
// grid: (64 b*h, 16 q-tiles); block 256 (4 waves x 32 q-rows).
// Round-9: T3 2-phase double-buffered pipeline over 64-kv chunks. LDS =
// 2 x (K 64x64 + Vt 64x64) = 32 KiB (unchanged -> occupancy unchanged).
// Iteration t: issue async global_load_lds for chunk t+1 into buf^1, compute
// chunk t from buf, ONE __syncthreads (its implicit vmcnt-drain now lands
// AFTER ~600cy of compute -> staging latency hidden; previously stage->sync
// exposed the full load latency to all waves 16x per block).
// Both QK^T and PV use full-rate mfma_f32_32x32x16_bf16. S^T = K*Q^T: C col =
// q = lane&31 -> ONE q per lane, softmax stats lane-local. P(f32) -> PV
// A-fragment via v_cvt_pk_bf16_f32 + v_permlane32_swap_b32 (T12, verified).
// Defer-max (THR=8 log2); l_run per-hi partial, reduced in epilogue.
__global__ __launch_bounds__(256) void attn_kernel(const __bf16* __restrict__ Qh,
                                                   const __bf16* __restrict__ Kh,
                                                   const __bf16* __restrict__ Vt,
                                                   __bf16* __restrict__ O) {
  __shared__ __bf16 Ks[2][64 * 64];   // [buf][kv][d], XOR-swizzled 16B blocks
  __shared__ __bf16 Vts[2][64 * 64];  // [buf][d][kv], XOR-swizzled 16B blocks

  const int tid = threadIdx.x;
  const int wave = tid >> 6, lane = tid & 63;
  const int l31 = lane & 31, hi = lane >> 5;
  const int qt = blockIdx.y, y = blockIdx.x;  // y = b*16+h
  const size_t hb = (size_t)y * 131072;
  const __bf16* Qb = Qh + hb + (size_t)qt * 128 * 64;
  const __bf16* Kb = Kh + hb;
  const __bf16* Vb = Vt + hb;
  const int wq0 = wave * 32;

  // staging geometry (per 64-kv chunk): 512 16B-slots each for K and Vt,
  // 256 threads -> 2 slots per thread per array.
  const int s0 = tid, s1 = 256 + tid;
  const int kr0 = s0 >> 3, kc0 = s0 & 7;   // K: row=kv, 8 d-blocks
  const int kr1 = s1 >> 3, kc1 = s1 & 7;
  // Vt: row=d (64 rows), 8 kv-blocks
  const int vr0 = kr0, vc0 = kc0, vr1 = kr1, vc1 = kc1;

  // Q fragments (B-operand of 32x32x16: col=q=lane&31, k=d=hi*8+j),
  // pre-scaled by 0.125*log2(e). 4 d-ksteps of 16.
  const float qscale = 0.125f * 1.44269504f;
  bf16x8v qf[4];
#pragma unroll
  for (int ks = 0; ks < 4; ks++) {
    bf16x8v q = *(const bf16x8v*)&Qb[(wq0 + l31) * 64 + ks * 16 + hi * 8];
#pragma unroll
    for (int j = 0; j < 8; j++) q[j] = (__bf16)((float)q[j] * qscale);
    qf[ks] = q;
  }

  // softmax state for q = wq0 + l31 (lane-local; l_run is a per-hi PARTIAL sum)
  float m_run = -INFINITY;
  float l_run = 0.f;
  f32x16 oacc[2];  // [d-tile]; col=d=nd*32+l31, row(reg)=(reg&3)+8*(reg>>2)+4*hi
#pragma unroll
  for (int nd = 0; nd < 2; nd++)
#pragma unroll
    for (int r = 0; r < 16; r++) oacc[nd][r] = 0.f;

  // prologue: stage chunk 0 into buf 0
  async_copy16(&Ks[0][s0 * 8], &Kb[(size_t)kr0 * 64 + (kc0 ^ (kr0 & 7)) * 8]);
  async_copy16(&Ks[0][s1 * 8], &Kb[(size_t)kr1 * 64 + (kc1 ^ (kr1 & 7)) * 8]);
  async_copy16(&Vts[0][s0 * 8], &Vb[(size_t)vr0 * 2048 + (vc0 ^ (vr0 & 7)) * 8]);
  async_copy16(&Vts[0][s1 * 8], &Vb[(size_t)vr1 * 2048 + (vc1 ^ (vr1 & 7)) * 8]);
  __syncthreads();

  for (int t = 0; t < 32; t++) {
    const int bsel = t & 1;
    if (t < 31) {  // issue async stage of chunk t+1 into the other buffer
      const int kv1 = (t + 1) * 64;
      async_copy16(&Ks[bsel ^ 1][s0 * 8],
                   &Kb[(size_t)(kv1 + kr0) * 64 + (kc0 ^ (kr0 & 7)) * 8]);
      async_copy16(&Ks[bsel ^ 1][s1 * 8],
                   &Kb[(size_t)(kv1 + kr1) * 64 + (kc1 ^ (kr1 & 7)) * 8]);
      async_copy16(&Vts[bsel ^ 1][s0 * 8],
                   &Vb[(size_t)vr0 * 2048 + kv1 + (vc0 ^ (vr0 & 7)) * 8]);
      async_copy16(&Vts[bsel ^ 1][s1 * 8],
                   &Vb[(size_t)vr1 * 2048 + kv1 + (vc1 ^ (vr1 & 7)) * 8]);
    }

    // ---- compute chunk t from buf bsel ----
    // S^T = K Q^T over 64 kv: st[kvt] (kv tile of 32), col=q=lane&31,
    // row = kvt*32 + (reg&3)+8*(reg>>2)+4*hi
    f32x16 st[2];
#pragma unroll
    for (int kvt = 0; kvt < 2; kvt++)
#pragma unroll
      for (int r = 0; r < 16; r++) st[kvt][r] = 0.f;
#pragma unroll
    for (int ks = 0; ks < 4; ks++) {
      const int sl = ((ks * 2 + hi) ^ (l31 & 7)) * 8;
      const bf16x8v kf0 = *(const bf16x8v*)&Ks[bsel][l31 * 64 + sl];
      const bf16x8v kf1 = *(const bf16x8v*)&Ks[bsel][(32 + l31) * 64 + sl];
      __builtin_amdgcn_s_setprio(1);
      st[0] = __builtin_amdgcn_mfma_f32_32x32x16_bf16(kf0, qf[ks], st[0], 0, 0, 0);
      st[1] = __builtin_amdgcn_mfma_f32_32x32x16_bf16(kf1, qf[ks], st[1], 0, 0, 0);
      __builtin_amdgcn_s_setprio(0);
    }

    // row max over own 32 st values (tree) + cross-hi swap
    float bmax[16];
#pragma unroll
    for (int j = 0; j < 16; j++) bmax[j] = fmaxf(st[0][j], st[1][j]);
#pragma unroll
    for (int s = 8; s > 0; s >>= 1)
#pragma unroll
      for (int j = 0; j < 8; j++)
        if (j < s) bmax[j] = fmaxf(bmax[j], bmax[j + s]);
    float rmax = bmax[0];
    rmax = fmaxf(rmax, __shfl_xor(rmax, 32));

    // defer-max: rescale only when some q-row's max grew by >8 (log2 units).
    // First chunk: m_run=-inf -> fires -> alpha=exp2(-inf)=0, state is 0.
    if (!__all(rmax - m_run <= 8.f)) {
      const float mnew = fmaxf(m_run, rmax);
      const float alpha = __builtin_amdgcn_exp2f(m_run - mnew);
      m_run = mnew;
      l_run *= alpha;  // partial sum scales uniformly
#pragma unroll
      for (int r = 0; r < 16; r++) {
        const float ar = __shfl(alpha, (r & 3) + 8 * (r >> 2) + 4 * hi);
        oacc[0][r] *= ar;
        oacc[1][r] *= ar;
      }
    }

    // PV: exp2 on the fly; P -> bf16 A-fragments via cvt_pk + permlane32_swap.
    float psum = 0.f;
#pragma unroll
    for (int kvt = 0; kvt < 2; kvt++) {
#pragma unroll
      for (int sub = 0; sub < 2; sub++) {
        const int ks2 = kvt * 2 + sub;      // kv kstep of 16 within this chunk
        const int vs = ((ks2 * 2 + hi) ^ (l31 & 7)) * 8;
        const bf16x8v vf0 = *(const bf16x8v*)&Vts[bsel][l31 * 64 + vs];
        const bf16x8v vf1 = *(const bf16x8v*)&Vts[bsel][(32 + l31) * 64 + vs];
        const int o = sub * 8;
        float p[8];
#pragma unroll
        for (int j = 0; j < 8; j++) {
          p[j] = __builtin_amdgcn_exp2f(st[kvt][o + j] - m_run);
          psum += p[j];
        }
        unsigned x0, y0, x1, y1;
        asm("v_cvt_pk_bf16_f32 %0, %1, %2" : "=v"(x0) : "v"(p[0]), "v"(p[1]));
        asm("v_cvt_pk_bf16_f32 %0, %1, %2" : "=v"(y0) : "v"(p[4]), "v"(p[5]));
        asm("v_cvt_pk_bf16_f32 %0, %1, %2" : "=v"(x1) : "v"(p[2]), "v"(p[3]));
        asm("v_cvt_pk_bf16_f32 %0, %1, %2" : "=v"(y1) : "v"(p[6]), "v"(p[7]));
        // {w0,w2} = swap(x0,y0); {w1,w3} = swap(x1,y1)
        asm("v_permlane32_swap_b32 %0, %1" : "+v"(x0), "+v"(y0));
        asm("v_permlane32_swap_b32 %0, %1" : "+v"(x1), "+v"(y1));
        union { unsigned u[4]; bf16x8v v; } af;
        af.u[0] = x0; af.u[1] = x1; af.u[2] = y0; af.u[3] = y1;
        __builtin_amdgcn_s_setprio(1);
        oacc[0] = __builtin_amdgcn_mfma_f32_32x32x16_bf16(af.v, vf0, oacc[0], 0, 0, 0);
        oacc[1] = __builtin_amdgcn_mfma_f32_32x32x16_bf16(af.v, vf1, oacc[1], 0, 0, 0);
        __builtin_amdgcn_s_setprio(0);
      }
    }
    l_run += psum;  // per-hi partial; reduced in epilogue

    __syncthreads();  // waves done with buf[bsel]; chunk t+1 loads drained
  }

  // epilogue: reduce l across the 2 hi replicas, broadcast 1/l to O-rows
  l_run += __shfl_xor(l_run, 32);
  const float linv = 1.f / l_run;
  const int b = y >> 4, h = y & 15;
#pragma unroll
  for (int r = 0; r < 16; r++) {
    const int q = (r & 3) + 8 * (r >> 2) + 4 * hi;
    const float inv = __shfl(linv, q);
    const int srow = qt * 128 + wq0 + q;
    const size_t base = ((size_t)(b * 2048 + srow)) * 1024 + h * 64;
    O[base + l31] = (__bf16)(oacc[0][r] * inv);
    O[base + 32 + l31] = (__bf16)(oacc[1][r] * inv);
  }
}

extern "C" void kernel_launch(void* const* d_in, const int* in_sizes, int n_in,
                              void* d_out, int out_size, void* d_ws, size_t ws_size,
                              hipStream_t stream) {
  const float* Qin = (const float*)d_in[0];
  const float* Kin = (const float*)d_in[1];
  const float* Vin = (const float*)d_in[2];
  const float* Wq = (const float*)d_in[3];
  const float* Wk = (const float*)d_in[4];
  const float* Wv = (const float*)d_in[5];
  const float* Wo = (const float*)d_in[6];
  float* out = (float*)d_out;

  __bf16* base = (__bf16*)d_ws;
  __bf16* Qbf = base;                    // 8388608
  __bf16* Kbf = base + 8388608;
  __bf16* Vbf = base + 16777216;
  __bf16* Wqb = base + 25165824;         // 1048576 each
  __bf16* Wkb = base + 26214400;
  __bf16* Wvb = base + 27262976;
  __bf16* Wob = base + 28311552;
  __bf16* Qh = base + 29360128;          // [B,H,S,dk]
  __bf16* Kh = base + 37748736;          // [B,H,S,dk]
  __bf16* Vt = base + 46137344;          // [B,H,dk,S]
  __bf16* AO = Qbf;                      // aliases Qbf (dead after gemm1)

  CastArgs ca;
  ca.s[0] = Qin; ca.s[1] = Kin; ca.s[2] = Vin;
  ca.s[3] = Wq;  ca.s[4] = Wk;  ca.s[5] = Wv;  ca.s[6] = Wo;
  ca.d[0] = Qbf; ca.d[1] = Kbf; ca.d[2] = Vbf;
  ca.d[3] = Wqb; ca.d[4] = Wkb; ca.d[5] = Wvb; ca.d[6] = Wob;
  cast_kernel<<<dim3(4096, 7), 256, 0, stream>>>(ca);

  const int M = 8192, N = 1024, K = 1024;
  dim3 bb(256);
  // Q and K projections batched: grid (bm=64, bn=8, z=2), XCD = bm%8
  gemm_bt<1, __bf16><<<dim3(64, 8, 2), bb, 0, stream>>>(Qbf, Wqb, Qh,
                                                        Kbf, Wkb, Kh, M, N, K);
  // V^T: swap operands -> Vt[n][s] = sum_k Wv[n][k] * Vin[s][k]  (M=1024, N=8192)
  // grid (bn=64, bm=8): XCD = bn%8, bn indexes the large operand (Vin) -- good.
  gemm_bt<3, __bf16><<<dim3(64, 8), bb, 0, stream>>>(Wvb, Vbf, Vt,
                                                     nullptr, nullptr, nullptr,
                                                     1024, 8192, K);
  attn_kernel<<<dim3(64, 16), bb, 0, stream>>>(Qh, Kh, Vt, AO);
  gemm_bt<0, float><<<dim3(64, 8), bb, 0, stream>>>(AO, Wob, out,
                                                    nullptr, nullptr, nullptr,
                                                    M, N, K);
}

// Round 4
// 338.609 us; speedup vs baseline: 1.1616x; 1.0945x over previous
//
#include <hip/hip_runtime.h>
#include <math.h>

typedef __bf16 bf16x8v __attribute__((ext_vector_type(8)));
typedef float f32x4 __attribute__((ext_vector_type(4)));
typedef float f32x16 __attribute__((ext_vector_type(16)));

__device__ __forceinline__ void async_copy16(void* lds, const void* g) {
  __builtin_amdgcn_global_load_lds(
      (const __attribute__((address_space(1))) void*)g,
      (__attribute__((address_space(3))) void*)lds, 16, 0, 0);
}

// ---- f32 -> bf16 cast, all 7 tensors in one launch ----
struct CastArgs {
  const float* s[7];
  __bf16* d[7];
};
__global__ __launch_bounds__(256) void cast_kernel(CastArgs a) {
  const int t = blockIdx.y;
  const int n = (t < 3) ? 8388608 : 1048576;
  const int i = (blockIdx.x * 256 + threadIdx.x) * 8;
  if (i >= n) return;
  const float4 v0 = *(const float4*)(a.s[t] + i);
  const float4 v1 = *(const float4*)(a.s[t] + i + 4);
  bf16x8v o;
  o[0] = (__bf16)v0.x; o[1] = (__bf16)v0.y; o[2] = (__bf16)v0.z; o[3] = (__bf16)v0.w;
  o[4] = (__bf16)v1.x; o[5] = (__bf16)v1.y; o[6] = (__bf16)v1.z; o[7] = (__bf16)v1.w;
  *(bf16x8v*)(a.d[t] + i) = o;
}

// C[m,n] = sum_k A[m,k] * B[n,k]   (A: MxK row-major, B: NxK row-major, bf16)
// LDS tiles XOR-swizzled at 16B-block granularity (see round-3 notes).
// XCD locality: blocks are round-robined to the 8 XCDs by linear block id.
// For MODE 0/1 the LARGE operand is A (8192xK, indexed by bm) -> bm must
// determine the XCD: grid (bm=64, bn=8[, z]) gives linear%8 = bm%8, so all 8
// bn-blocks sharing an A row-block land on ONE XCD (A fetched once from HBM,
// was 8x = 134 MB/GEMM in r6). MODE 3's large operand is B (indexed by bn =
// blockIdx.x, grid (64,8)) -- already the good orientation.
// blockIdx.z selects the (A2,B2,C2) set (batched Q+K projections).
// MODE 0: C[row*N+col] (float, final output)
// MODE 1: split heads -> [B,H,S,dk]  (row=b*2048+s, col=h*64+d)
// MODE 3: V^T heads -> [B,H,dk,S]    (row=h*64+d [M=1024], col=b*2048+s [N=8192])
template <int MODE, typename OutT>
__global__ __launch_bounds__(256) void gemm_bt(const __bf16* A, const __bf16* B,
                                               OutT* C,
                                               const __bf16* A2, const __bf16* B2,
                                               OutT* C2,
                                               int M, int N, int K) {
  __shared__ __bf16 As[128 * 64];
  __shared__ __bf16 Bs[128 * 64];
  if (blockIdx.z == 1) { A = A2; B = B2; C = C2; }
  const int tid = threadIdx.x;
  const int wave = tid >> 6, lane = tid & 63;
  const int lgrp = lane >> 4, lmod = lane & 15;
  const int bm = (MODE == 3 ? blockIdx.y : blockIdx.x) * 128;
  const int bn = (MODE == 3 ? blockIdx.x : blockIdx.y) * 128;
  const int wm = (wave >> 1) * 64, wn = (wave & 1) * 64;

  f32x4 acc[4][4];
#pragma unroll
  for (int mi = 0; mi < 4; mi++)
#pragma unroll
    for (int ni = 0; ni < 4; ni++)
#pragma unroll
      for (int r = 0; r < 4; r++) acc[mi][ni][r] = 0.f;

  for (int kt = 0; kt < K; kt += 64) {
#pragma unroll
    for (int i = 0; i < 4; i++) {
      const int s = i * 256 + tid;      // 16B-block slot in 128x8-block tile
      const int r = s >> 3, cb = s & 7;
      const int gc = (cb ^ (r & 7)) * 8;  // swizzled global column (elements)
      async_copy16(&As[s * 8], &A[(size_t)(bm + r) * K + kt + gc]);
      async_copy16(&Bs[s * 8], &B[(size_t)(bn + r) * K + kt + gc]);
    }
    __syncthreads();
#pragma unroll
    for (int ks = 0; ks < 2; ks++) {
      bf16x8v af[4], bf[4];
#pragma unroll
      for (int mi = 0; mi < 4; mi++) {
        const int row = wm + mi * 16 + lmod;
        af[mi] = *(const bf16x8v*)&As[row * 64 + ((ks * 4 + lgrp) ^ (row & 7)) * 8];
      }
#pragma unroll
      for (int ni = 0; ni < 4; ni++) {
        const int row = wn + ni * 16 + lmod;
        bf[ni] = *(const bf16x8v*)&Bs[row * 64 + ((ks * 4 + lgrp) ^ (row & 7)) * 8];
      }
#pragma unroll
      for (int mi = 0; mi < 4; mi++)
#pragma unroll
        for (int ni = 0; ni < 4; ni++)
          acc[mi][ni] = __builtin_amdgcn_mfma_f32_16x16x32_bf16(af[mi], bf[ni],
                                                                acc[mi][ni], 0, 0, 0);
    }
    __syncthreads();
  }

#pragma unroll
  for (int mi = 0; mi < 4; mi++)
#pragma unroll
    for (int ni = 0; ni < 4; ni++)
#pragma unroll
      for (int r = 0; r < 4; r++) {
        const int row = bm + wm + mi * 16 + lgrp * 4 + r;
        const int col = bn + wn + ni * 16 + lmod;
        if (MODE == 0) {
          C[(size_t)row * N + col] = (OutT)acc[mi][ni][r];
        } else if (MODE == 1) {
          C[(size_t)(row >> 11) * 2097152 + (size_t)(col >> 6) * 131072 +
            (size_t)(row & 2047) * 64 + (col & 63)] = (OutT)acc[mi][ni][r];
        } else {  // MODE 3: Vt[b][h][d][s], row=h*64+d, col=b*2048+s (coalesced in s)
          C[(size_t)(col >> 11) * 2097152 + (size_t)(row >> 6) * 131072 +
            (size_t)(row & 63) * 2048 + (col & 2047)] = (OutT)acc[mi][ni][r];
        }
      }
}

// Flash attention, S^T formulation (P never touches LDS), 32x32 MFMA form.
// Qh,Kh: [B,H,S,dk]; Vt: [B,H,dk,S]; O: [B,S,H*dk]  (all bf16)
// grid: (64 b*h, 16 q-tiles); block 256 (4 waves x 32 q-rows).
// Round-10: double-buffer with STATICALLY-NAMED LDS buffers (Ks0/Ks1,
// Vts0/Vts1) and an explicitly 2x-unrolled pipeline. Round-9's dynamically
// indexed Ks[bsel^1] prefetch aliased (to LLVM) the Ks[bsel] ds_reads ->
// the memory legalizer inserted s_waitcnt vmcnt(0) before the compute's
// first ds_read, serializing every chunk behind its own prefetch (142us,
// worse than the non-pipelined 129us). Distinct LDS objects => provable
// NoAlias => prefetch stays in flight across the compute; the only vmcnt
// drain is inside the phase-end __syncthreads, landing after ~700cy of
// MFMA+softmax. Staging addresses hoisted to 4 loop-invariant base
// pointers (chunk step: K +4096 el, Vt +64 el).
// Both QK^T and PV use full-rate mfma_f32_32x32x16_bf16. S^T = K*Q^T: C col =
// q = lane&31 -> ONE q per lane, softmax stats lane-local. P(f32) -> PV
// A-fragment via v_cvt_pk_bf16_f32 + v_permlane32_swap_b32 (T12, verified).
// Defer-max (THR=8 log2); l_run per-hi partial, reduced in epilogue.
__global__ __launch_bounds__(256) void attn_kernel(const __bf16* __restrict__ Qh,
                                                   const __bf16* __restrict__ Kh,
                                                   const __bf16* __restrict__ Vt,
                                                   __bf16* __restrict__ O) {
  __shared__ __bf16 Ks0[64 * 64];   // [kv][d], XOR-swizzled 16B blocks
  __shared__ __bf16 Ks1[64 * 64];
  __shared__ __bf16 Vts0[64 * 64];  // [d][kv], XOR-swizzled 16B blocks
  __shared__ __bf16 Vts1[64 * 64];

  const int tid = threadIdx.x;
  const int wave = tid >> 6, lane = tid & 63;
  const int l31 = lane & 31, hi = lane >> 5;
  const int qt = blockIdx.y, y = blockIdx.x;  // y = b*16+h
  const size_t hb = (size_t)y * 131072;
  const __bf16* Qb = Qh + hb + (size_t)qt * 128 * 64;
  const __bf16* Kb = Kh + hb;
  const __bf16* Vb = Vt + hb;
  const int wq0 = wave * 32;

  // staging geometry (per 64-kv chunk): 512 16B-slots each for K and Vt,
  // 256 threads -> 2 slots per thread per array.
  const int s0 = tid, s1 = 256 + tid;
  const int kr0 = s0 >> 3, kc0 = s0 & 7;   // K: row=kv, 8 d-blocks
  const int kr1 = s1 >> 3, kc1 = s1 & 7;
  // loop-invariant staging source base pointers (chunk c: K +c*4096, Vt +c*64)
  const __bf16* kSrc0 = Kb + (size_t)kr0 * 64 + (kc0 ^ (kr0 & 7)) * 8;
  const __bf16* kSrc1 = Kb + (size_t)kr1 * 64 + (kc1 ^ (kr1 & 7)) * 8;
  const __bf16* vSrc0 = Vb + (size_t)kr0 * 2048 + (kc0 ^ (kr0 & 7)) * 8;
  const __bf16* vSrc1 = Vb + (size_t)kr1 * 2048 + (kc1 ^ (kr1 & 7)) * 8;

  // Q fragments (B-operand of 32x32x16: col=q=lane&31, k=d=hi*8+j),
  // pre-scaled by 0.125*log2(e). 4 d-ksteps of 16.
  const float qscale = 0.125f * 1.44269504f;
  bf16x8v qf[4];
#pragma unroll
  for (int ks = 0; ks < 4; ks++) {
    bf16x8v q = *(const bf16x8v*)&Qb[(wq0 + l31) * 64 + ks * 16 + hi * 8];
#pragma unroll
    for (int j = 0; j < 8; j++) q[j] = (__bf16)((float)q[j] * qscale);
    qf[ks] = q;
  }

  // softmax state for q = wq0 + l31 (lane-local; l_run is a per-hi PARTIAL sum)
  float m_run = -INFINITY;
  float l_run = 0.f;
  f32x16 oacc[2];  // [d-tile]; col=d=nd*32+l31, row(reg)=(reg&3)+8*(reg>>2)+4*hi
#pragma unroll
  for (int nd = 0; nd < 2; nd++)
#pragma unroll
    for (int r = 0; r < 16; r++) oacc[nd][r] = 0.f;

  auto STAGE = [&](int c, __bf16* Kd, __bf16* Vd) {
    async_copy16(&Kd[s0 * 8], kSrc0 + (size_t)c * 4096);
    async_copy16(&Kd[s1 * 8], kSrc1 + (size_t)c * 4096);
    async_copy16(&Vd[s0 * 8], vSrc0 + (size_t)c * 64);
    async_copy16(&Vd[s1 * 8], vSrc1 + (size_t)c * 64);
  };

  auto COMPUTE = [&](const __bf16* Kbuf, const __bf16* Vbuf) {
    // S^T = K Q^T over 64 kv: st[kvt] (kv tile of 32), col=q=lane&31,
    // row = kvt*32 + (reg&3)+8*(reg>>2)+4*hi
    f32x16 st[2];
#pragma unroll
    for (int kvt = 0; kvt < 2; kvt++)
#pragma unroll
      for (int r = 0; r < 16; r++) st[kvt][r] = 0.f;
#pragma unroll
    for (int ks = 0; ks < 4; ks++) {
      const int sl = ((ks * 2 + hi) ^ (l31 & 7)) * 8;
      const bf16x8v kf0 = *(const bf16x8v*)&Kbuf[l31 * 64 + sl];
      const bf16x8v kf1 = *(const bf16x8v*)&Kbuf[(32 + l31) * 64 + sl];
      __builtin_amdgcn_s_setprio(1);
      st[0] = __builtin_amdgcn_mfma_f32_32x32x16_bf16(kf0, qf[ks], st[0], 0, 0, 0);
      st[1] = __builtin_amdgcn_mfma_f32_32x32x16_bf16(kf1, qf[ks], st[1], 0, 0, 0);
      __builtin_amdgcn_s_setprio(0);
    }

    // row max over own 32 st values (tree) + cross-hi swap
    float bmax[16];
#pragma unroll
    for (int j = 0; j < 16; j++) bmax[j] = fmaxf(st[0][j], st[1][j]);
#pragma unroll
    for (int s = 8; s > 0; s >>= 1)
#pragma unroll
      for (int j = 0; j < 8; j++)
        if (j < s) bmax[j] = fmaxf(bmax[j], bmax[j + s]);
    float rmax = bmax[0];
    rmax = fmaxf(rmax, __shfl_xor(rmax, 32));

    // defer-max: rescale only when some q-row's max grew by >8 (log2 units).
    // First chunk: m_run=-inf -> fires -> alpha=exp2(-inf)=0, state is 0.
    if (!__all(rmax - m_run <= 8.f)) {
      const float mnew = fmaxf(m_run, rmax);
      const float alpha = __builtin_amdgcn_exp2f(m_run - mnew);
      m_run = mnew;
      l_run *= alpha;  // partial sum scales uniformly
#pragma unroll
      for (int r = 0; r < 16; r++) {
        const float ar = __shfl(alpha, (r & 3) + 8 * (r >> 2) + 4 * hi);
        oacc[0][r] *= ar;
        oacc[1][r] *= ar;
      }
    }

    // PV: exp2 on the fly; P -> bf16 A-fragments via cvt_pk + permlane32_swap.
    float psum = 0.f;
#pragma unroll
    for (int kvt = 0; kvt < 2; kvt++) {
#pragma unroll
      for (int sub = 0; sub < 2; sub++) {
        const int ks2 = kvt * 2 + sub;      // kv kstep of 16 within this chunk
        const int vs = ((ks2 * 2 + hi) ^ (l31 & 7)) * 8;
        const bf16x8v vf0 = *(const bf16x8v*)&Vbuf[l31 * 64 + vs];
        const bf16x8v vf1 = *(const bf16x8v*)&Vbuf[(32 + l31) * 64 + vs];
        const int o = sub * 8;
        float p[8];
#pragma unroll
        for (int j = 0; j < 8; j++) {
          p[j] = __builtin_amdgcn_exp2f(st[kvt][o + j] - m_run);
          psum += p[j];
        }
        unsigned x0, y0, x1, y1;
        asm("v_cvt_pk_bf16_f32 %0, %1, %2" : "=v"(x0) : "v"(p[0]), "v"(p[1]));
        asm("v_cvt_pk_bf16_f32 %0, %1, %2" : "=v"(y0) : "v"(p[4]), "v"(p[5]));
        asm("v_cvt_pk_bf16_f32 %0, %1, %2" : "=v"(x1) : "v"(p[2]), "v"(p[3]));
        asm("v_cvt_pk_bf16_f32 %0, %1, %2" : "=v"(y1) : "v"(p[6]), "v"(p[7]));
        // {w0,w2} = swap(x0,y0); {w1,w3} = swap(x1,y1)
        asm("v_permlane32_swap_b32 %0, %1" : "+v"(x0), "+v"(y0));
        asm("v_permlane32_swap_b32 %0, %1" : "+v"(x1), "+v"(y1));
        union { unsigned u[4]; bf16x8v v; } af;
        af.u[0] = x0; af.u[1] = x1; af.u[2] = y0; af.u[3] = y1;
        __builtin_amdgcn_s_setprio(1);
        oacc[0] = __builtin_amdgcn_mfma_f32_32x32x16_bf16(af.v, vf0, oacc[0], 0, 0, 0);
        oacc[1] = __builtin_amdgcn_mfma_f32_32x32x16_bf16(af.v, vf1, oacc[1], 0, 0, 0);
        __builtin_amdgcn_s_setprio(0);
      }
    }
    l_run += psum;  // per-hi partial; reduced in epilogue
  };

  // ---- 2x-unrolled double-buffered pipeline over 32 chunks of 64 kv ----
  STAGE(0, Ks0, Vts0);
  __syncthreads();
#pragma unroll 1
  for (int t = 0; t < 15; t++) {
    STAGE(2 * t + 1, Ks1, Vts1);   // writes Ks1/Vts1: last read before prev sync
    COMPUTE(Ks0, Vts0);
    __syncthreads();               // drains prefetch (hidden under compute)
    STAGE(2 * t + 2, Ks0, Vts0);
    COMPUTE(Ks1, Vts1);
    __syncthreads();
  }
  STAGE(31, Ks1, Vts1);
  COMPUTE(Ks0, Vts0);
  __syncthreads();
  COMPUTE(Ks1, Vts1);

  // epilogue: reduce l across the 2 hi replicas, broadcast 1/l to O-rows
  l_run += __shfl_xor(l_run, 32);
  const float linv = 1.f / l_run;
  const int b = y >> 4, h = y & 15;
#pragma unroll
  for (int r = 0; r < 16; r++) {
    const int q = (r & 3) + 8 * (r >> 2) + 4 * hi;
    const float inv = __shfl(linv, q);
    const int srow = qt * 128 + wq0 + q;
    const size_t base = ((size_t)(b * 2048 + srow)) * 1024 + h * 64;
    O[base + l31] = (__bf16)(oacc[0][r] * inv);
    O[base + 32 + l31] = (__bf16)(oacc[1][r] * inv);
  }
}

extern "C" void kernel_launch(void* const* d_in, const int* in_sizes, int n_in,
                              void* d_out, int out_size, void* d_ws, size_t ws_size,
                              hipStream_t stream) {
  const float* Qin = (const float*)d_in[0];
  const float* Kin = (const float*)d_in[1];
  const float* Vin = (const float*)d_in[2];
  const float* Wq = (const float*)d_in[3];
  const float* Wk = (const float*)d_in[4];
  const float* Wv = (const float*)d_in[5];
  const float* Wo = (const float*)d_in[6];
  float* out = (float*)d_out;

  __bf16* base = (__bf16*)d_ws;
  __bf16* Qbf = base;                    // 8388608
  __bf16* Kbf = base + 8388608;
  __bf16* Vbf = base + 16777216;
  __bf16* Wqb = base + 25165824;         // 1048576 each
  __bf16* Wkb = base + 26214400;
  __bf16* Wvb = base + 27262976;
  __bf16* Wob = base + 28311552;
  __bf16* Qh = base + 29360128;          // [B,H,S,dk]
  __bf16* Kh = base + 37748736;          // [B,H,S,dk]
  __bf16* Vt = base + 46137344;          // [B,H,dk,S]
  __bf16* AO = Qbf;                      // aliases Qbf (dead after gemm1)

  CastArgs ca;
  ca.s[0] = Qin; ca.s[1] = Kin; ca.s[2] = Vin;
  ca.s[3] = Wq;  ca.s[4] = Wk;  ca.s[5] = Wv;  ca.s[6] = Wo;
  ca.d[0] = Qbf; ca.d[1] = Kbf; ca.d[2] = Vbf;
  ca.d[3] = Wqb; ca.d[4] = Wkb; ca.d[5] = Wvb; ca.d[6] = Wob;
  cast_kernel<<<dim3(4096, 7), 256, 0, stream>>>(ca);

  const int M = 8192, N = 1024, K = 1024;
  dim3 bb(256);
  // Q and K projections batched: grid (bm=64, bn=8, z=2), XCD = bm%8
  gemm_bt<1, __bf16><<<dim3(64, 8, 2), bb, 0, stream>>>(Qbf, Wqb, Qh,
                                                        Kbf, Wkb, Kh, M, N, K);
  // V^T: swap operands -> Vt[n][s] = sum_k Wv[n][k] * Vin[s][k]  (M=1024, N=8192)
  // grid (bn=64, bm=8): XCD = bn%8, bn indexes the large operand (Vin) -- good.
  gemm_bt<3, __bf16><<<dim3(64, 8), bb, 0, stream>>>(Wvb, Vbf, Vt,
                                                     nullptr, nullptr, nullptr,
                                                     1024, 8192, K);
  attn_kernel<<<dim3(64, 16), bb, 0, stream>>>(Qh, Kh, Vt, AO);
  gemm_bt<0, float><<<dim3(64, 8), bb, 0, stream>>>(AO, Wob, out,
                                                    nullptr, nullptr, nullptr,
                                                    M, N, K);
}

// Round 5
// 329.733 us; speedup vs baseline: 1.1929x; 1.0269x over previous
//
#include <hip/hip_runtime.h>
#include <math.h>

typedef __bf16 bf16x8v __attribute__((ext_vector_type(8)));
typedef float f32x4 __attribute__((ext_vector_type(4)));
typedef float f32x16 __attribute__((ext_vector_type(16)));

__device__ __forceinline__ void async_copy16(void* lds, const void* g) {
  __builtin_amdgcn_global_load_lds(
      (const __attribute__((address_space(1))) void*)g,
      (__attribute__((address_space(3))) void*)lds, 16, 0, 0);
}

// ---- f32 -> bf16 cast, all 7 tensors in one launch ----
struct CastArgs {
  const float* s[7];
  __bf16* d[7];
};
__global__ __launch_bounds__(256) void cast_kernel(CastArgs a) {
  const int t = blockIdx.y;
  const int n = (t < 3) ? 8388608 : 1048576;
  const int i = (blockIdx.x * 256 + threadIdx.x) * 8;
  if (i >= n) return;
  const float4 v0 = *(const float4*)(a.s[t] + i);
  const float4 v1 = *(const float4*)(a.s[t] + i + 4);
  bf16x8v o;
  o[0] = (__bf16)v0.x; o[1] = (__bf16)v0.y; o[2] = (__bf16)v0.z; o[3] = (__bf16)v0.w;
  o[4] = (__bf16)v1.x; o[5] = (__bf16)v1.y; o[6] = (__bf16)v1.z; o[7] = (__bf16)v1.w;
  *(bf16x8v*)(a.d[t] + i) = o;
}

// C[m,n] = sum_k A[m,k] * B[n,k]   (A: MxK row-major, B: NxK row-major, bf16)
// LDS tiles XOR-swizzled at 16B-block granularity.
// Round-11: same static double-buffer pipeline as the attn kernel (round-10):
// 4 named LDS arrays (As0/Bs0/As1/Bs1, 64 KiB) so LLVM proves NoAlias between
// the chunk-t+1 global_load_lds prefetch and the chunk-t ds_reads -> prefetch
// stays in flight across the whole compute phase; the only vmcnt drain is the
// phase-end __syncthreads. Previously every 64-wide K-step exposed the full
// global->LDS latency (STAGE -> sync -> compute). Occupancy: 64 KiB LDS caps
// at 2 blocks/CU = what the 512-block grids already had (no loss); the z=2
// batched launch drops 4->2 resident but gains latency hiding (round-4-proven
// trade). Staging source pointers hoisted (chunk step = +64 elements).
// XCD locality: blocks are round-robined to the 8 XCDs by linear block id.
// For MODE 0/1 the LARGE operand is A (8192xK, indexed by bm) -> grid
// (bm=64, bn=8[, z]) gives linear%8 = bm%8: all 8 bn-blocks sharing an A
// row-block land on ONE XCD. MODE 3's large operand is B (indexed by bn =
// blockIdx.x, grid (64,8)) -- already the good orientation.
// blockIdx.z selects the (A2,B2,C2) set (batched Q+K projections).
// MODE 0: C[row*N+col] (float, final output)
// MODE 1: split heads -> [B,H,S,dk]  (row=b*2048+s, col=h*64+d)
// MODE 3: V^T heads -> [B,H,dk,S]    (row=h*64+d [M=1024], col=b*2048+s [N=8192])
template <int MODE, typename OutT>
__global__ __launch_bounds__(256) void gemm_bt(const __bf16* A, const __bf16* B,
                                               OutT* C,
                                               const __bf16* A2, const __bf16* B2,
                                               OutT* C2,
                                               int M, int N, int K) {
  __shared__ __bf16 As0[128 * 64];
  __shared__ __bf16 Bs0[128 * 64];
  __shared__ __bf16 As1[128 * 64];
  __shared__ __bf16 Bs1[128 * 64];
  if (blockIdx.z == 1) { A = A2; B = B2; C = C2; }
  const int tid = threadIdx.x;
  const int wave = tid >> 6, lane = tid & 63;
  const int lgrp = lane >> 4, lmod = lane & 15;
  const int bm = (MODE == 3 ? blockIdx.y : blockIdx.x) * 128;
  const int bn = (MODE == 3 ? blockIdx.x : blockIdx.y) * 128;
  const int wm = (wave >> 1) * 64, wn = (wave & 1) * 64;

  // staging geometry: 1024 16B-slots per array per chunk, 4 per thread.
  // slot s -> row r = s>>3, col-block cb = s&7, swizzled col (cb^(r&7))*8.
  const __bf16* aSrc[4];
  const __bf16* bSrc[4];
  int slot[4];
#pragma unroll
  for (int i = 0; i < 4; i++) {
    const int s = i * 256 + tid;
    const int r = s >> 3, cb = s & 7;
    const int gc = (cb ^ (r & 7)) * 8;
    slot[i] = s * 8;
    aSrc[i] = A + (size_t)(bm + r) * K + gc;
    bSrc[i] = B + (size_t)(bn + r) * K + gc;
  }

  f32x4 acc[4][4];
#pragma unroll
  for (int mi = 0; mi < 4; mi++)
#pragma unroll
    for (int ni = 0; ni < 4; ni++)
#pragma unroll
      for (int r = 0; r < 4; r++) acc[mi][ni][r] = 0.f;

  auto STAGE = [&](int c, __bf16* Ad, __bf16* Bd) {
#pragma unroll
    for (int i = 0; i < 4; i++) {
      async_copy16(&Ad[slot[i]], aSrc[i] + (size_t)c * 64);
      async_copy16(&Bd[slot[i]], bSrc[i] + (size_t)c * 64);
    }
  };

  auto COMPUTE = [&](const __bf16* Abuf, const __bf16* Bbuf) {
#pragma unroll
    for (int ks = 0; ks < 2; ks++) {
      bf16x8v af[4], bf[4];
#pragma unroll
      for (int mi = 0; mi < 4; mi++) {
        const int row = wm + mi * 16 + lmod;
        af[mi] = *(const bf16x8v*)&Abuf[row * 64 + ((ks * 4 + lgrp) ^ (row & 7)) * 8];
      }
#pragma unroll
      for (int ni = 0; ni < 4; ni++) {
        const int row = wn + ni * 16 + lmod;
        bf[ni] = *(const bf16x8v*)&Bbuf[row * 64 + ((ks * 4 + lgrp) ^ (row & 7)) * 8];
      }
#pragma unroll
      for (int mi = 0; mi < 4; mi++)
#pragma unroll
        for (int ni = 0; ni < 4; ni++)
          acc[mi][ni] = __builtin_amdgcn_mfma_f32_16x16x32_bf16(af[mi], bf[ni],
                                                                acc[mi][ni], 0, 0, 0);
    }
  };

  // ---- 2x-unrolled double-buffered pipeline over 16 chunks of 64 K ----
  STAGE(0, As0, Bs0);
  __syncthreads();
#pragma unroll 1
  for (int t = 0; t < 7; t++) {
    STAGE(2 * t + 1, As1, Bs1);
    COMPUTE(As0, Bs0);
    __syncthreads();               // drains prefetch (hidden under compute)
    STAGE(2 * t + 2, As0, Bs0);
    COMPUTE(As1, Bs1);
    __syncthreads();
  }
  STAGE(15, As1, Bs1);
  COMPUTE(As0, Bs0);
  __syncthreads();
  COMPUTE(As1, Bs1);

#pragma unroll
  for (int mi = 0; mi < 4; mi++)
#pragma unroll
    for (int ni = 0; ni < 4; ni++)
#pragma unroll
      for (int r = 0; r < 4; r++) {
        const int row = bm + wm + mi * 16 + lgrp * 4 + r;
        const int col = bn + wn + ni * 16 + lmod;
        if (MODE == 0) {
          C[(size_t)row * N + col] = (OutT)acc[mi][ni][r];
        } else if (MODE == 1) {
          C[(size_t)(row >> 11) * 2097152 + (size_t)(col >> 6) * 131072 +
            (size_t)(row & 2047) * 64 + (col & 63)] = (OutT)acc[mi][ni][r];
        } else {  // MODE 3: Vt[b][h][d][s], row=h*64+d, col=b*2048+s (coalesced in s)
          C[(size_t)(col >> 11) * 2097152 + (size_t)(row >> 6) * 131072 +
            (size_t)(row & 63) * 2048 + (col & 2047)] = (OutT)acc[mi][ni][r];
        }
      }
}

// Flash attention, S^T formulation (P never touches LDS), 32x32 MFMA form.
// Qh,Kh: [B,H,S,dk]; Vt: [B,H,dk,S]; O: [B,S,H*dk]  (all bf16)
// grid: (64 b*h, 16 q-tiles); block 256 (4 waves x 32 q-rows).
// Round-10: double-buffer with STATICALLY-NAMED LDS buffers (Ks0/Ks1,
// Vts0/Vts1) and an explicitly 2x-unrolled pipeline (round-9's dynamically
// indexed buffers aliased, forcing a serializing vmcnt(0); static objects
// give provable NoAlias -> prefetch rides over compute; 142us -> 108us).
// Both QK^T and PV use full-rate mfma_f32_32x32x16_bf16. S^T = K*Q^T: C col =
// q = lane&31 -> ONE q per lane, softmax stats lane-local. P(f32) -> PV
// A-fragment via v_cvt_pk_bf16_f32 + v_permlane32_swap_b32 (T12, verified).
// Defer-max (THR=8 log2); l_run per-hi partial, reduced in epilogue.
__global__ __launch_bounds__(256) void attn_kernel(const __bf16* __restrict__ Qh,
                                                   const __bf16* __restrict__ Kh,
                                                   const __bf16* __restrict__ Vt,
                                                   __bf16* __restrict__ O) {
  __shared__ __bf16 Ks0[64 * 64];   // [kv][d], XOR-swizzled 16B blocks
  __shared__ __bf16 Ks1[64 * 64];
  __shared__ __bf16 Vts0[64 * 64];  // [d][kv], XOR-swizzled 16B blocks
  __shared__ __bf16 Vts1[64 * 64];

  const int tid = threadIdx.x;
  const int wave = tid >> 6, lane = tid & 63;
  const int l31 = lane & 31, hi = lane >> 5;
  const int qt = blockIdx.y, y = blockIdx.x;  // y = b*16+h
  const size_t hb = (size_t)y * 131072;
  const __bf16* Qb = Qh + hb + (size_t)qt * 128 * 64;
  const __bf16* Kb = Kh + hb;
  const __bf16* Vb = Vt + hb;
  const int wq0 = wave * 32;

  // staging geometry (per 64-kv chunk): 512 16B-slots each for K and Vt,
  // 256 threads -> 2 slots per thread per array.
  const int s0 = tid, s1 = 256 + tid;
  const int kr0 = s0 >> 3, kc0 = s0 & 7;   // K: row=kv, 8 d-blocks
  const int kr1 = s1 >> 3, kc1 = s1 & 7;
  // loop-invariant staging source base pointers (chunk c: K +c*4096, Vt +c*64)
  const __bf16* kSrc0 = Kb + (size_t)kr0 * 64 + (kc0 ^ (kr0 & 7)) * 8;
  const __bf16* kSrc1 = Kb + (size_t)kr1 * 64 + (kc1 ^ (kr1 & 7)) * 8;
  const __bf16* vSrc0 = Vb + (size_t)kr0 * 2048 + (kc0 ^ (kr0 & 7)) * 8;
  const __bf16* vSrc1 = Vb + (size_t)kr1 * 2048 + (kc1 ^ (kr1 & 7)) * 8;

  // Q fragments (B-operand of 32x32x16: col=q=lane&31, k=d=hi*8+j),
  // pre-scaled by 0.125*log2(e). 4 d-ksteps of 16.
  const float qscale = 0.125f * 1.44269504f;
  bf16x8v qf[4];
#pragma unroll
  for (int ks = 0; ks < 4; ks++) {
    bf16x8v q = *(const bf16x8v*)&Qb[(wq0 + l31) * 64 + ks * 16 + hi * 8];
#pragma unroll
    for (int j = 0; j < 8; j++) q[j] = (__bf16)((float)q[j] * qscale);
    qf[ks] = q;
  }

  // softmax state for q = wq0 + l31 (lane-local; l_run is a per-hi PARTIAL sum)
  float m_run = -INFINITY;
  float l_run = 0.f;
  f32x16 oacc[2];  // [d-tile]; col=d=nd*32+l31, row(reg)=(reg&3)+8*(reg>>2)+4*hi
#pragma unroll
  for (int nd = 0; nd < 2; nd++)
#pragma unroll
    for (int r = 0; r < 16; r++) oacc[nd][r] = 0.f;

  auto STAGE = [&](int c, __bf16* Kd, __bf16* Vd) {
    async_copy16(&Kd[s0 * 8], kSrc0 + (size_t)c * 4096);
    async_copy16(&Kd[s1 * 8], kSrc1 + (size_t)c * 4096);
    async_copy16(&Vd[s0 * 8], vSrc0 + (size_t)c * 64);
    async_copy16(&Vd[s1 * 8], vSrc1 + (size_t)c * 64);
  };

  auto COMPUTE = [&](const __bf16* Kbuf, const __bf16* Vbuf) {
    // S^T = K Q^T over 64 kv: st[kvt] (kv tile of 32), col=q=lane&31,
    // row = kvt*32 + (reg&3)+8*(reg>>2)+4*hi
    f32x16 st[2];
#pragma unroll
    for (int kvt = 0; kvt < 2; kvt++)
#pragma unroll
      for (int r = 0; r < 16; r++) st[kvt][r] = 0.f;
#pragma unroll
    for (int ks = 0; ks < 4; ks++) {
      const int sl = ((ks * 2 + hi) ^ (l31 & 7)) * 8;
      const bf16x8v kf0 = *(const bf16x8v*)&Kbuf[l31 * 64 + sl];
      const bf16x8v kf1 = *(const bf16x8v*)&Kbuf[(32 + l31) * 64 + sl];
      __builtin_amdgcn_s_setprio(1);
      st[0] = __builtin_amdgcn_mfma_f32_32x32x16_bf16(kf0, qf[ks], st[0], 0, 0, 0);
      st[1] = __builtin_amdgcn_mfma_f32_32x32x16_bf16(kf1, qf[ks], st[1], 0, 0, 0);
      __builtin_amdgcn_s_setprio(0);
    }

    // row max over own 32 st values (tree) + cross-hi swap
    float bmax[16];
#pragma unroll
    for (int j = 0; j < 16; j++) bmax[j] = fmaxf(st[0][j], st[1][j]);
#pragma unroll
    for (int s = 8; s > 0; s >>= 1)
#pragma unroll
      for (int j = 0; j < 8; j++)
        if (j < s) bmax[j] = fmaxf(bmax[j], bmax[j + s]);
    float rmax = bmax[0];
    rmax = fmaxf(rmax, __shfl_xor(rmax, 32));

    // defer-max: rescale only when some q-row's max grew by >8 (log2 units).
    // First chunk: m_run=-inf -> fires -> alpha=exp2(-inf)=0, state is 0.
    if (!__all(rmax - m_run <= 8.f)) {
      const float mnew = fmaxf(m_run, rmax);
      const float alpha = __builtin_amdgcn_exp2f(m_run - mnew);
      m_run = mnew;
      l_run *= alpha;  // partial sum scales uniformly
#pragma unroll
      for (int r = 0; r < 16; r++) {
        const float ar = __shfl(alpha, (r & 3) + 8 * (r >> 2) + 4 * hi);
        oacc[0][r] *= ar;
        oacc[1][r] *= ar;
      }
    }

    // PV: exp2 on the fly; P -> bf16 A-fragments via cvt_pk + permlane32_swap.
    float psum = 0.f;
#pragma unroll
    for (int kvt = 0; kvt < 2; kvt++) {
#pragma unroll
      for (int sub = 0; sub < 2; sub++) {
        const int ks2 = kvt * 2 + sub;      // kv kstep of 16 within this chunk
        const int vs = ((ks2 * 2 + hi) ^ (l31 & 7)) * 8;
        const bf16x8v vf0 = *(const bf16x8v*)&Vbuf[l31 * 64 + vs];
        const bf16x8v vf1 = *(const bf16x8v*)&Vbuf[(32 + l31) * 64 + vs];
        const int o = sub * 8;
        float p[8];
#pragma unroll
        for (int j = 0; j < 8; j++) {
          p[j] = __builtin_amdgcn_exp2f(st[kvt][o + j] - m_run);
          psum += p[j];
        }
        unsigned x0, y0, x1, y1;
        asm("v_cvt_pk_bf16_f32 %0, %1, %2" : "=v"(x0) : "v"(p[0]), "v"(p[1]));
        asm("v_cvt_pk_bf16_f32 %0, %1, %2" : "=v"(y0) : "v"(p[4]), "v"(p[5]));
        asm("v_cvt_pk_bf16_f32 %0, %1, %2" : "=v"(x1) : "v"(p[2]), "v"(p[3]));
        asm("v_cvt_pk_bf16_f32 %0, %1, %2" : "=v"(y1) : "v"(p[6]), "v"(p[7]));
        // {w0,w2} = swap(x0,y0); {w1,w3} = swap(x1,y1)
        asm("v_permlane32_swap_b32 %0, %1" : "+v"(x0), "+v"(y0));
        asm("v_permlane32_swap_b32 %0, %1" : "+v"(x1), "+v"(y1));
        union { unsigned u[4]; bf16x8v v; } af;
        af.u[0] = x0; af.u[1] = x1; af.u[2] = y0; af.u[3] = y1;
        __builtin_amdgcn_s_setprio(1);
        oacc[0] = __builtin_amdgcn_mfma_f32_32x32x16_bf16(af.v, vf0, oacc[0], 0, 0, 0);
        oacc[1] = __builtin_amdgcn_mfma_f32_32x32x16_bf16(af.v, vf1, oacc[1], 0, 0, 0);
        __builtin_amdgcn_s_setprio(0);
      }
    }
    l_run += psum;  // per-hi partial; reduced in epilogue
  };

  // ---- 2x-unrolled double-buffered pipeline over 32 chunks of 64 kv ----
  STAGE(0, Ks0, Vts0);
  __syncthreads();
#pragma unroll 1
  for (int t = 0; t < 15; t++) {
    STAGE(2 * t + 1, Ks1, Vts1);   // writes Ks1/Vts1: last read before prev sync
    COMPUTE(Ks0, Vts0);
    __syncthreads();               // drains prefetch (hidden under compute)
    STAGE(2 * t + 2, Ks0, Vts0);
    COMPUTE(Ks1, Vts1);
    __syncthreads();
  }
  STAGE(31, Ks1, Vts1);
  COMPUTE(Ks0, Vts0);
  __syncthreads();
  COMPUTE(Ks1, Vts1);

  // epilogue: reduce l across the 2 hi replicas, broadcast 1/l to O-rows
  l_run += __shfl_xor(l_run, 32);
  const float linv = 1.f / l_run;
  const int b = y >> 4, h = y & 15;
#pragma unroll
  for (int r = 0; r < 16; r++) {
    const int q = (r & 3) + 8 * (r >> 2) + 4 * hi;
    const float inv = __shfl(linv, q);
    const int srow = qt * 128 + wq0 + q;
    const size_t base = ((size_t)(b * 2048 + srow)) * 1024 + h * 64;
    O[base + l31] = (__bf16)(oacc[0][r] * inv);
    O[base + 32 + l31] = (__bf16)(oacc[1][r] * inv);
  }
}

extern "C" void kernel_launch(void* const* d_in, const int* in_sizes, int n_in,
                              void* d_out, int out_size, void* d_ws, size_t ws_size,
                              hipStream_t stream) {
  const float* Qin = (const float*)d_in[0];
  const float* Kin = (const float*)d_in[1];
  const float* Vin = (const float*)d_in[2];
  const float* Wq = (const float*)d_in[3];
  const float* Wk = (const float*)d_in[4];
  const float* Wv = (const float*)d_in[5];
  const float* Wo = (const float*)d_in[6];
  float* out = (float*)d_out;

  __bf16* base = (__bf16*)d_ws;
  __bf16* Qbf = base;                    // 8388608
  __bf16* Kbf = base + 8388608;
  __bf16* Vbf = base + 16777216;
  __bf16* Wqb = base + 25165824;         // 1048576 each
  __bf16* Wkb = base + 26214400;
  __bf16* Wvb = base + 27262976;
  __bf16* Wob = base + 28311552;
  __bf16* Qh = base + 29360128;          // [B,H,S,dk]
  __bf16* Kh = base + 37748736;          // [B,H,S,dk]
  __bf16* Vt = base + 46137344;          // [B,H,dk,S]
  __bf16* AO = Qbf;                      // aliases Qbf (dead after gemm1)

  CastArgs ca;
  ca.s[0] = Qin; ca.s[1] = Kin; ca.s[2] = Vin;
  ca.s[3] = Wq;  ca.s[4] = Wk;  ca.s[5] = Wv;  ca.s[6] = Wo;
  ca.d[0] = Qbf; ca.d[1] = Kbf; ca.d[2] = Vbf;
  ca.d[3] = Wqb; ca.d[4] = Wkb; ca.d[5] = Wvb; ca.d[6] = Wob;
  cast_kernel<<<dim3(4096, 7), 256, 0, stream>>>(ca);

  const int M = 8192, N = 1024, K = 1024;
  dim3 bb(256);
  // Q and K projections batched: grid (bm=64, bn=8, z=2), XCD = bm%8
  gemm_bt<1, __bf16><<<dim3(64, 8, 2), bb, 0, stream>>>(Qbf, Wqb, Qh,
                                                        Kbf, Wkb, Kh, M, N, K);
  // V^T: swap operands -> Vt[n][s] = sum_k Wv[n][k] * Vin[s][k]  (M=1024, N=8192)
  // grid (bn=64, bm=8): XCD = bn%8, bn indexes the large operand (Vin) -- good.
  gemm_bt<3, __bf16><<<dim3(64, 8), bb, 0, stream>>>(Wvb, Vbf, Vt,
                                                     nullptr, nullptr, nullptr,
                                                     1024, 8192, K);
  attn_kernel<<<dim3(64, 16), bb, 0, stream>>>(Qh, Kh, Vt, AO);
  gemm_bt<0, float><<<dim3(64, 8), bb, 0, stream>>>(AO, Wob, out,
                                                    nullptr, nullptr, nullptr,
                                                    M, N, K);
}

// Round 6
// 320.456 us; speedup vs baseline: 1.2274x; 1.0289x over previous
//
#include <hip/hip_runtime.h>
#include <math.h>

typedef __bf16 bf16x8v __attribute__((ext_vector_type(8)));
typedef float f32x4 __attribute__((ext_vector_type(4)));
typedef float f32x16 __attribute__((ext_vector_type(16)));

__device__ __forceinline__ void async_copy16(void* lds, const void* g) {
  __builtin_amdgcn_global_load_lds(
      (const __attribute__((address_space(1))) void*)g,
      (__attribute__((address_space(3))) void*)lds, 16, 0, 0);
}

// ---- f32 -> bf16 cast, all 7 tensors in one launch ----
struct CastArgs {
  const float* s[7];
  __bf16* d[7];
};
__global__ __launch_bounds__(256) void cast_kernel(CastArgs a) {
  const int t = blockIdx.y;
  const int n = (t < 3) ? 8388608 : 1048576;
  const int i = (blockIdx.x * 256 + threadIdx.x) * 8;
  if (i >= n) return;
  const float4 v0 = *(const float4*)(a.s[t] + i);
  const float4 v1 = *(const float4*)(a.s[t] + i + 4);
  bf16x8v o;
  o[0] = (__bf16)v0.x; o[1] = (__bf16)v0.y; o[2] = (__bf16)v0.z; o[3] = (__bf16)v0.w;
  o[4] = (__bf16)v1.x; o[5] = (__bf16)v1.y; o[6] = (__bf16)v1.z; o[7] = (__bf16)v1.w;
  *(bf16x8v*)(a.d[t] + i) = o;
}

// C[m,n] = sum_k A[m,k] * B[n,k]   (A: MxK row-major, B: NxK row-major, bf16)
// LDS tiles XOR-swizzled at 16B-block granularity.
// Round-12: 8-WAVE blocks (512 threads) at the same 128x128 tile. The single
// GEMMs are grid-limited to 2 blocks/CU (512-block grids); with 4-wave blocks
// that was 8 waves/CU = 2/SIMD -- too little TLP to hide ds_read/MFMA latency
// and barrier convergence (measured ~46us/GEMM vs ~12-19us structural floor).
// 8-wave blocks double it to 16 waves/CU at identical LDS (64 KiB dbuf) and
// identical per-CU staging/MFMA volume. Wave w owns a 64x32 sub-tile:
// wm=(w>>2)*64, wn=(w&3)*32, acc[4][2] (32 VGPR -> fits 4 waves/SIMD cap).
// Static double-buffer pipeline (round-11): 4 named LDS arrays so LLVM proves
// NoAlias between the chunk-t+1 global_load_lds prefetch and chunk-t ds_reads;
// the only vmcnt drain is the phase-end __syncthreads, hidden under compute.
// XCD locality: linear%8 keyed to the LARGE operand's block index (see grids).
// blockIdx.z selects the (A2,B2,C2) set (batched Q+K projections).
// MODE 0: C[row*N+col] (float, final output)
// MODE 1: split heads -> [B,H,S,dk]  (row=b*2048+s, col=h*64+d)
// MODE 3: V^T heads -> [B,H,dk,S]    (row=h*64+d [M=1024], col=b*2048+s [N=8192])
template <int MODE, typename OutT>
__global__ __launch_bounds__(512) void gemm_bt(const __bf16* A, const __bf16* B,
                                               OutT* C,
                                               const __bf16* A2, const __bf16* B2,
                                               OutT* C2,
                                               int M, int N, int K) {
  __shared__ __bf16 As0[128 * 64];
  __shared__ __bf16 Bs0[128 * 64];
  __shared__ __bf16 As1[128 * 64];
  __shared__ __bf16 Bs1[128 * 64];
  if (blockIdx.z == 1) { A = A2; B = B2; C = C2; }
  const int tid = threadIdx.x;
  const int wave = tid >> 6, lane = tid & 63;
  const int lgrp = lane >> 4, lmod = lane & 15;
  const int bm = (MODE == 3 ? blockIdx.y : blockIdx.x) * 128;
  const int bn = (MODE == 3 ? blockIdx.x : blockIdx.y) * 128;
  const int wm = (wave >> 2) * 64, wn = (wave & 3) * 32;

  // staging geometry: 1024 16B-slots per array per chunk, 2 per thread.
  // slot s -> row r = s>>3, col-block cb = s&7, swizzled col (cb^(r&7))*8.
  const __bf16* aSrc[2];
  const __bf16* bSrc[2];
  int slot[2];
#pragma unroll
  for (int i = 0; i < 2; i++) {
    const int s = i * 512 + tid;
    const int r = s >> 3, cb = s & 7;
    const int gc = (cb ^ (r & 7)) * 8;
    slot[i] = s * 8;
    aSrc[i] = A + (size_t)(bm + r) * K + gc;
    bSrc[i] = B + (size_t)(bn + r) * K + gc;
  }

  f32x4 acc[4][2];
#pragma unroll
  for (int mi = 0; mi < 4; mi++)
#pragma unroll
    for (int ni = 0; ni < 2; ni++)
#pragma unroll
      for (int r = 0; r < 4; r++) acc[mi][ni][r] = 0.f;

  auto STAGE = [&](int c, __bf16* Ad, __bf16* Bd) {
#pragma unroll
    for (int i = 0; i < 2; i++) {
      async_copy16(&Ad[slot[i]], aSrc[i] + (size_t)c * 64);
      async_copy16(&Bd[slot[i]], bSrc[i] + (size_t)c * 64);
    }
  };

  auto COMPUTE = [&](const __bf16* Abuf, const __bf16* Bbuf) {
#pragma unroll
    for (int ks = 0; ks < 2; ks++) {
      bf16x8v af[4], bf[2];
#pragma unroll
      for (int mi = 0; mi < 4; mi++) {
        const int row = wm + mi * 16 + lmod;
        af[mi] = *(const bf16x8v*)&Abuf[row * 64 + ((ks * 4 + lgrp) ^ (row & 7)) * 8];
      }
#pragma unroll
      for (int ni = 0; ni < 2; ni++) {
        const int row = wn + ni * 16 + lmod;
        bf[ni] = *(const bf16x8v*)&Bbuf[row * 64 + ((ks * 4 + lgrp) ^ (row & 7)) * 8];
      }
#pragma unroll
      for (int mi = 0; mi < 4; mi++)
#pragma unroll
        for (int ni = 0; ni < 2; ni++)
          acc[mi][ni] = __builtin_amdgcn_mfma_f32_16x16x32_bf16(af[mi], bf[ni],
                                                                acc[mi][ni], 0, 0, 0);
    }
  };

  // ---- 2x-unrolled double-buffered pipeline over 16 chunks of 64 K ----
  STAGE(0, As0, Bs0);
  __syncthreads();
#pragma unroll 1
  for (int t = 0; t < 7; t++) {
    STAGE(2 * t + 1, As1, Bs1);
    COMPUTE(As0, Bs0);
    __syncthreads();               // drains prefetch (hidden under compute)
    STAGE(2 * t + 2, As0, Bs0);
    COMPUTE(As1, Bs1);
    __syncthreads();
  }
  STAGE(15, As1, Bs1);
  COMPUTE(As0, Bs0);
  __syncthreads();
  COMPUTE(As1, Bs1);

#pragma unroll
  for (int mi = 0; mi < 4; mi++)
#pragma unroll
    for (int ni = 0; ni < 2; ni++)
#pragma unroll
      for (int r = 0; r < 4; r++) {
        const int row = bm + wm + mi * 16 + lgrp * 4 + r;
        const int col = bn + wn + ni * 16 + lmod;
        if (MODE == 0) {
          C[(size_t)row * N + col] = (OutT)acc[mi][ni][r];
        } else if (MODE == 1) {
          C[(size_t)(row >> 11) * 2097152 + (size_t)(col >> 6) * 131072 +
            (size_t)(row & 2047) * 64 + (col & 63)] = (OutT)acc[mi][ni][r];
        } else {  // MODE 3: Vt[b][h][d][s], row=h*64+d, col=b*2048+s (coalesced in s)
          C[(size_t)(col >> 11) * 2097152 + (size_t)(row >> 6) * 131072 +
            (size_t)(row & 63) * 2048 + (col & 2047)] = (OutT)acc[mi][ni][r];
        }
      }
}

// Flash attention, S^T formulation (P never touches LDS), 32x32 MFMA form.
// Qh,Kh: [B,H,S,dk]; Vt: [B,H,dk,S]; O: [B,S,H*dk]  (all bf16)
// grid: (64 b*h, 16 q-tiles); block 256 (4 waves x 32 q-rows).
// Round-10: double-buffer with STATICALLY-NAMED LDS buffers (Ks0/Ks1,
// Vts0/Vts1) and an explicitly 2x-unrolled pipeline (round-9's dynamically
// indexed buffers aliased, forcing a serializing vmcnt(0); static objects
// give provable NoAlias -> prefetch rides over compute; 142us -> 108us).
// Both QK^T and PV use full-rate mfma_f32_32x32x16_bf16. S^T = K*Q^T: C col =
// q = lane&31 -> ONE q per lane, softmax stats lane-local. P(f32) -> PV
// A-fragment via v_cvt_pk_bf16_f32 + v_permlane32_swap_b32 (T12, verified).
// Defer-max (THR=8 log2); l_run per-hi partial, reduced in epilogue.
__global__ __launch_bounds__(256) void attn_kernel(const __bf16* __restrict__ Qh,
                                                   const __bf16* __restrict__ Kh,
                                                   const __bf16* __restrict__ Vt,
                                                   __bf16* __restrict__ O) {
  __shared__ __bf16 Ks0[64 * 64];   // [kv][d], XOR-swizzled 16B blocks
  __shared__ __bf16 Ks1[64 * 64];
  __shared__ __bf16 Vts0[64 * 64];  // [d][kv], XOR-swizzled 16B blocks
  __shared__ __bf16 Vts1[64 * 64];

  const int tid = threadIdx.x;
  const int wave = tid >> 6, lane = tid & 63;
  const int l31 = lane & 31, hi = lane >> 5;
  const int qt = blockIdx.y, y = blockIdx.x;  // y = b*16+h
  const size_t hb = (size_t)y * 131072;
  const __bf16* Qb = Qh + hb + (size_t)qt * 128 * 64;
  const __bf16* Kb = Kh + hb;
  const __bf16* Vb = Vt + hb;
  const int wq0 = wave * 32;

  // staging geometry (per 64-kv chunk): 512 16B-slots each for K and Vt,
  // 256 threads -> 2 slots per thread per array.
  const int s0 = tid, s1 = 256 + tid;
  const int kr0 = s0 >> 3, kc0 = s0 & 7;   // K: row=kv, 8 d-blocks
  const int kr1 = s1 >> 3, kc1 = s1 & 7;
  // loop-invariant staging source base pointers (chunk c: K +c*4096, Vt +c*64)
  const __bf16* kSrc0 = Kb + (size_t)kr0 * 64 + (kc0 ^ (kr0 & 7)) * 8;
  const __bf16* kSrc1 = Kb + (size_t)kr1 * 64 + (kc1 ^ (kr1 & 7)) * 8;
  const __bf16* vSrc0 = Vb + (size_t)kr0 * 2048 + (kc0 ^ (kr0 & 7)) * 8;
  const __bf16* vSrc1 = Vb + (size_t)kr1 * 2048 + (kc1 ^ (kr1 & 7)) * 8;

  // Q fragments (B-operand of 32x32x16: col=q=lane&31, k=d=hi*8+j),
  // pre-scaled by 0.125*log2(e). 4 d-ksteps of 16.
  const float qscale = 0.125f * 1.44269504f;
  bf16x8v qf[4];
#pragma unroll
  for (int ks = 0; ks < 4; ks++) {
    bf16x8v q = *(const bf16x8v*)&Qb[(wq0 + l31) * 64 + ks * 16 + hi * 8];
#pragma unroll
    for (int j = 0; j < 8; j++) q[j] = (__bf16)((float)q[j] * qscale);
    qf[ks] = q;
  }

  // softmax state for q = wq0 + l31 (lane-local; l_run is a per-hi PARTIAL sum)
  float m_run = -INFINITY;
  float l_run = 0.f;
  f32x16 oacc[2];  // [d-tile]; col=d=nd*32+l31, row(reg)=(reg&3)+8*(reg>>2)+4*hi
#pragma unroll
  for (int nd = 0; nd < 2; nd++)
#pragma unroll
    for (int r = 0; r < 16; r++) oacc[nd][r] = 0.f;

  auto STAGE = [&](int c, __bf16* Kd, __bf16* Vd) {
    async_copy16(&Kd[s0 * 8], kSrc0 + (size_t)c * 4096);
    async_copy16(&Kd[s1 * 8], kSrc1 + (size_t)c * 4096);
    async_copy16(&Vd[s0 * 8], vSrc0 + (size_t)c * 64);
    async_copy16(&Vd[s1 * 8], vSrc1 + (size_t)c * 64);
  };

  auto COMPUTE = [&](const __bf16* Kbuf, const __bf16* Vbuf) {
    // S^T = K Q^T over 64 kv: st[kvt] (kv tile of 32), col=q=lane&31,
    // row = kvt*32 + (reg&3)+8*(reg>>2)+4*hi
    f32x16 st[2];
#pragma unroll
    for (int kvt = 0; kvt < 2; kvt++)
#pragma unroll
      for (int r = 0; r < 16; r++) st[kvt][r] = 0.f;
#pragma unroll
    for (int ks = 0; ks < 4; ks++) {
      const int sl = ((ks * 2 + hi) ^ (l31 & 7)) * 8;
      const bf16x8v kf0 = *(const bf16x8v*)&Kbuf[l31 * 64 + sl];
      const bf16x8v kf1 = *(const bf16x8v*)&Kbuf[(32 + l31) * 64 + sl];
      __builtin_amdgcn_s_setprio(1);
      st[0] = __builtin_amdgcn_mfma_f32_32x32x16_bf16(kf0, qf[ks], st[0], 0, 0, 0);
      st[1] = __builtin_amdgcn_mfma_f32_32x32x16_bf16(kf1, qf[ks], st[1], 0, 0, 0);
      __builtin_amdgcn_s_setprio(0);
    }

    // row max over own 32 st values (tree) + cross-hi swap
    float bmax[16];
#pragma unroll
    for (int j = 0; j < 16; j++) bmax[j] = fmaxf(st[0][j], st[1][j]);
#pragma unroll
    for (int s = 8; s > 0; s >>= 1)
#pragma unroll
      for (int j = 0; j < 8; j++)
        if (j < s) bmax[j] = fmaxf(bmax[j], bmax[j + s]);
    float rmax = bmax[0];
    rmax = fmaxf(rmax, __shfl_xor(rmax, 32));

    // defer-max: rescale only when some q-row's max grew by >8 (log2 units).
    // First chunk: m_run=-inf -> fires -> alpha=exp2(-inf)=0, state is 0.
    if (!__all(rmax - m_run <= 8.f)) {
      const float mnew = fmaxf(m_run, rmax);
      const float alpha = __builtin_amdgcn_exp2f(m_run - mnew);
      m_run = mnew;
      l_run *= alpha;  // partial sum scales uniformly
#pragma unroll
      for (int r = 0; r < 16; r++) {
        const float ar = __shfl(alpha, (r & 3) + 8 * (r >> 2) + 4 * hi);
        oacc[0][r] *= ar;
        oacc[1][r] *= ar;
      }
    }

    // PV: exp2 on the fly; P -> bf16 A-fragments via cvt_pk + permlane32_swap.
    float psum = 0.f;
#pragma unroll
    for (int kvt = 0; kvt < 2; kvt++) {
#pragma unroll
      for (int sub = 0; sub < 2; sub++) {
        const int ks2 = kvt * 2 + sub;      // kv kstep of 16 within this chunk
        const int vs = ((ks2 * 2 + hi) ^ (l31 & 7)) * 8;
        const bf16x8v vf0 = *(const bf16x8v*)&Vbuf[l31 * 64 + vs];
        const bf16x8v vf1 = *(const bf16x8v*)&Vbuf[(32 + l31) * 64 + vs];
        const int o = sub * 8;
        float p[8];
#pragma unroll
        for (int j = 0; j < 8; j++) {
          p[j] = __builtin_amdgcn_exp2f(st[kvt][o + j] - m_run);
          psum += p[j];
        }
        unsigned x0, y0, x1, y1;
        asm("v_cvt_pk_bf16_f32 %0, %1, %2" : "=v"(x0) : "v"(p[0]), "v"(p[1]));
        asm("v_cvt_pk_bf16_f32 %0, %1, %2" : "=v"(y0) : "v"(p[4]), "v"(p[5]));
        asm("v_cvt_pk_bf16_f32 %0, %1, %2" : "=v"(x1) : "v"(p[2]), "v"(p[3]));
        asm("v_cvt_pk_bf16_f32 %0, %1, %2" : "=v"(y1) : "v"(p[6]), "v"(p[7]));
        // {w0,w2} = swap(x0,y0); {w1,w3} = swap(x1,y1)
        asm("v_permlane32_swap_b32 %0, %1" : "+v"(x0), "+v"(y0));
        asm("v_permlane32_swap_b32 %0, %1" : "+v"(x1), "+v"(y1));
        union { unsigned u[4]; bf16x8v v; } af;
        af.u[0] = x0; af.u[1] = x1; af.u[2] = y0; af.u[3] = y1;
        __builtin_amdgcn_s_setprio(1);
        oacc[0] = __builtin_amdgcn_mfma_f32_32x32x16_bf16(af.v, vf0, oacc[0], 0, 0, 0);
        oacc[1] = __builtin_amdgcn_mfma_f32_32x32x16_bf16(af.v, vf1, oacc[1], 0, 0, 0);
        __builtin_amdgcn_s_setprio(0);
      }
    }
    l_run += psum;  // per-hi partial; reduced in epilogue
  };

  // ---- 2x-unrolled double-buffered pipeline over 32 chunks of 64 kv ----
  STAGE(0, Ks0, Vts0);
  __syncthreads();
#pragma unroll 1
  for (int t = 0; t < 15; t++) {
    STAGE(2 * t + 1, Ks1, Vts1);   // writes Ks1/Vts1: last read before prev sync
    COMPUTE(Ks0, Vts0);
    __syncthreads();               // drains prefetch (hidden under compute)
    STAGE(2 * t + 2, Ks0, Vts0);
    COMPUTE(Ks1, Vts1);
    __syncthreads();
  }
  STAGE(31, Ks1, Vts1);
  COMPUTE(Ks0, Vts0);
  __syncthreads();
  COMPUTE(Ks1, Vts1);

  // epilogue: reduce l across the 2 hi replicas, broadcast 1/l to O-rows
  l_run += __shfl_xor(l_run, 32);
  const float linv = 1.f / l_run;
  const int b = y >> 4, h = y & 15;
#pragma unroll
  for (int r = 0; r < 16; r++) {
    const int q = (r & 3) + 8 * (r >> 2) + 4 * hi;
    const float inv = __shfl(linv, q);
    const int srow = qt * 128 + wq0 + q;
    const size_t base = ((size_t)(b * 2048 + srow)) * 1024 + h * 64;
    O[base + l31] = (__bf16)(oacc[0][r] * inv);
    O[base + 32 + l31] = (__bf16)(oacc[1][r] * inv);
  }
}

extern "C" void kernel_launch(void* const* d_in, const int* in_sizes, int n_in,
                              void* d_out, int out_size, void* d_ws, size_t ws_size,
                              hipStream_t stream) {
  const float* Qin = (const float*)d_in[0];
  const float* Kin = (const float*)d_in[1];
  const float* Vin = (const float*)d_in[2];
  const float* Wq = (const float*)d_in[3];
  const float* Wk = (const float*)d_in[4];
  const float* Wv = (const float*)d_in[5];
  const float* Wo = (const float*)d_in[6];
  float* out = (float*)d_out;

  __bf16* base = (__bf16*)d_ws;
  __bf16* Qbf = base;                    // 8388608
  __bf16* Kbf = base + 8388608;
  __bf16* Vbf = base + 16777216;
  __bf16* Wqb = base + 25165824;         // 1048576 each
  __bf16* Wkb = base + 26214400;
  __bf16* Wvb = base + 27262976;
  __bf16* Wob = base + 28311552;
  __bf16* Qh = base + 29360128;          // [B,H,S,dk]
  __bf16* Kh = base + 37748736;          // [B,H,S,dk]
  __bf16* Vt = base + 46137344;          // [B,H,dk,S]
  __bf16* AO = Qbf;                      // aliases Qbf (dead after gemm1)

  CastArgs ca;
  ca.s[0] = Qin; ca.s[1] = Kin; ca.s[2] = Vin;
  ca.s[3] = Wq;  ca.s[4] = Wk;  ca.s[5] = Wv;  ca.s[6] = Wo;
  ca.d[0] = Qbf; ca.d[1] = Kbf; ca.d[2] = Vbf;
  ca.d[3] = Wqb; ca.d[4] = Wkb; ca.d[5] = Wvb; ca.d[6] = Wob;
  cast_kernel<<<dim3(4096, 7), 256, 0, stream>>>(ca);

  const int M = 8192, N = 1024, K = 1024;
  dim3 bb(512);
  // Q and K projections batched: grid (bm=64, bn=8, z=2), XCD = bm%8
  gemm_bt<1, __bf16><<<dim3(64, 8, 2), bb, 0, stream>>>(Qbf, Wqb, Qh,
                                                        Kbf, Wkb, Kh, M, N, K);
  // V^T: swap operands -> Vt[n][s] = sum_k Wv[n][k] * Vin[s][k]  (M=1024, N=8192)
  // grid (bn=64, bm=8): XCD = bn%8, bn indexes the large operand (Vin) -- good.
  gemm_bt<3, __bf16><<<dim3(64, 8), bb, 0, stream>>>(Wvb, Vbf, Vt,
                                                     nullptr, nullptr, nullptr,
                                                     1024, 8192, K);
  attn_kernel<<<dim3(64, 16), dim3(256), 0, stream>>>(Qh, Kh, Vt, AO);
  gemm_bt<0, float><<<dim3(64, 8), bb, 0, stream>>>(AO, Wob, out,
                                                    nullptr, nullptr, nullptr,
                                                    M, N, K);
}

// Round 7
// 318.832 us; speedup vs baseline: 1.2336x; 1.0051x over previous
//
#include <hip/hip_runtime.h>
#include <math.h>

typedef __bf16 bf16x8v __attribute__((ext_vector_type(8)));
typedef float f32x2 __attribute__((ext_vector_type(2)));
typedef float f32x4 __attribute__((ext_vector_type(4)));
typedef float f32x16 __attribute__((ext_vector_type(16)));

__device__ __forceinline__ void async_copy16(void* lds, const void* g) {
  __builtin_amdgcn_global_load_lds(
      (const __attribute__((address_space(1))) void*)g,
      (__attribute__((address_space(3))) void*)lds, 16, 0, 0);
}

__device__ __forceinline__ f32x2 pk_add(f32x2 a, f32x2 b) {
  f32x2 d;
  asm("v_pk_add_f32 %0, %1, %2" : "=v"(d) : "v"(a), "v"(b));
  return d;
}
__device__ __forceinline__ float max3f(float a, float b, float c) {
  float d;
  asm("v_max3_f32 %0, %1, %2, %3" : "=v"(d) : "v"(a), "v"(b), "v"(c));
  return d;
}

// ---- f32 -> bf16 cast, all 7 tensors in one launch ----
struct CastArgs {
  const float* s[7];
  __bf16* d[7];
};
__global__ __launch_bounds__(256) void cast_kernel(CastArgs a) {
  const int t = blockIdx.y;
  const int n = (t < 3) ? 8388608 : 1048576;
  const int i = (blockIdx.x * 256 + threadIdx.x) * 8;
  if (i >= n) return;
  const float4 v0 = *(const float4*)(a.s[t] + i);
  const float4 v1 = *(const float4*)(a.s[t] + i + 4);
  bf16x8v o;
  o[0] = (__bf16)v0.x; o[1] = (__bf16)v0.y; o[2] = (__bf16)v0.z; o[3] = (__bf16)v0.w;
  o[4] = (__bf16)v1.x; o[5] = (__bf16)v1.y; o[6] = (__bf16)v1.z; o[7] = (__bf16)v1.w;
  *(bf16x8v*)(a.d[t] + i) = o;
}

// C[m,n] = sum_k A[m,k] * B[n,k]   (A: MxK row-major, B: NxK row-major, bf16)
// LDS tiles XOR-swizzled at 16B-block granularity.
// Round-13: the V^T projection is MERGED into the z-batched launch (z=3):
// all three projections share grid shape (64,8) -- z=2 just swaps the bm/bn
// roles (large operand = B = Vbf) and uses the MODE-3 epilogue. One fewer
// launch; V^T's 512 blocks backfill the QK tranche stragglers. XCD locality
// preserved: linear%8 = blockIdx.x%8 and x indexes the LARGE operand for all
// three z (A row-block for z<2, B row-block for z=2).
// 8-wave blocks (round-12), static double-buffer pipeline (round-11: named
// LDS arrays -> provable NoAlias -> prefetch rides over compute; only vmcnt
// drain is the phase-end __syncthreads).
// MODE 0: C[row*N+col] (float, final output)
// MODE 1: z<2 split heads -> [B,H,S,dk]; z==2 V^T heads -> [B,H,dk,S]
// MODE 3: V^T heads -> [B,H,dk,S]    (row=h*64+d [M=1024], col=b*2048+s)
template <int MODE, typename OutT>
__global__ __launch_bounds__(512) void gemm_bt(const __bf16* A, const __bf16* B,
                                               OutT* C,
                                               const __bf16* A2, const __bf16* B2,
                                               OutT* C2,
                                               const __bf16* A3, const __bf16* B3,
                                               OutT* C3,
                                               int M, int N, int K) {
  __shared__ __bf16 As0[128 * 64];
  __shared__ __bf16 Bs0[128 * 64];
  __shared__ __bf16 As1[128 * 64];
  __shared__ __bf16 Bs1[128 * 64];
  const bool vz = (MODE == 1 && blockIdx.z == 2);  // V^T sub-launch
  if (MODE == 1) {
    if (blockIdx.z == 1) { A = A2; B = B2; C = C2; }
    else if (blockIdx.z == 2) { A = A3; B = B3; C = C3; }
  }
  const int tid = threadIdx.x;
  const int wave = tid >> 6, lane = tid & 63;
  const int lgrp = lane >> 4, lmod = lane & 15;
  const int bm = ((MODE == 3 || vz) ? blockIdx.y : blockIdx.x) * 128;
  const int bn = ((MODE == 3 || vz) ? blockIdx.x : blockIdx.y) * 128;
  const int wm = (wave >> 2) * 64, wn = (wave & 3) * 32;

  // staging geometry: 1024 16B-slots per array per chunk, 2 per thread.
  // slot s -> row r = s>>3, col-block cb = s&7, swizzled col (cb^(r&7))*8.
  const __bf16* aSrc[2];
  const __bf16* bSrc[2];
  int slot[2];
#pragma unroll
  for (int i = 0; i < 2; i++) {
    const int s = i * 512 + tid;
    const int r = s >> 3, cb = s & 7;
    const int gc = (cb ^ (r & 7)) * 8;
    slot[i] = s * 8;
    aSrc[i] = A + (size_t)(bm + r) * K + gc;
    bSrc[i] = B + (size_t)(bn + r) * K + gc;
  }

  f32x4 acc[4][2];
#pragma unroll
  for (int mi = 0; mi < 4; mi++)
#pragma unroll
    for (int ni = 0; ni < 2; ni++)
#pragma unroll
      for (int r = 0; r < 4; r++) acc[mi][ni][r] = 0.f;

  auto STAGE = [&](int c, __bf16* Ad, __bf16* Bd) {
#pragma unroll
    for (int i = 0; i < 2; i++) {
      async_copy16(&Ad[slot[i]], aSrc[i] + (size_t)c * 64);
      async_copy16(&Bd[slot[i]], bSrc[i] + (size_t)c * 64);
    }
  };

  auto COMPUTE = [&](const __bf16* Abuf, const __bf16* Bbuf) {
#pragma unroll
    for (int ks = 0; ks < 2; ks++) {
      bf16x8v af[4], bf[2];
#pragma unroll
      for (int mi = 0; mi < 4; mi++) {
        const int row = wm + mi * 16 + lmod;
        af[mi] = *(const bf16x8v*)&Abuf[row * 64 + ((ks * 4 + lgrp) ^ (row & 7)) * 8];
      }
#pragma unroll
      for (int ni = 0; ni < 2; ni++) {
        const int row = wn + ni * 16 + lmod;
        bf[ni] = *(const bf16x8v*)&Bbuf[row * 64 + ((ks * 4 + lgrp) ^ (row & 7)) * 8];
      }
#pragma unroll
      for (int mi = 0; mi < 4; mi++)
#pragma unroll
        for (int ni = 0; ni < 2; ni++)
          acc[mi][ni] = __builtin_amdgcn_mfma_f32_16x16x32_bf16(af[mi], bf[ni],
                                                                acc[mi][ni], 0, 0, 0);
    }
  };

  // ---- 2x-unrolled double-buffered pipeline over 16 chunks of 64 K ----
  STAGE(0, As0, Bs0);
  __syncthreads();
#pragma unroll 1
  for (int t = 0; t < 7; t++) {
    STAGE(2 * t + 1, As1, Bs1);
    COMPUTE(As0, Bs0);
    __syncthreads();               // drains prefetch (hidden under compute)
    STAGE(2 * t + 2, As0, Bs0);
    COMPUTE(As1, Bs1);
    __syncthreads();
  }
  STAGE(15, As1, Bs1);
  COMPUTE(As0, Bs0);
  __syncthreads();
  COMPUTE(As1, Bs1);

#pragma unroll
  for (int mi = 0; mi < 4; mi++)
#pragma unroll
    for (int ni = 0; ni < 2; ni++)
#pragma unroll
      for (int r = 0; r < 4; r++) {
        const int row = bm + wm + mi * 16 + lgrp * 4 + r;
        const int col = bn + wn + ni * 16 + lmod;
        if (MODE == 0) {
          C[(size_t)row * N + col] = (OutT)acc[mi][ni][r];
        } else if (MODE == 1 && !vz) {
          C[(size_t)(row >> 11) * 2097152 + (size_t)(col >> 6) * 131072 +
            (size_t)(row & 2047) * 64 + (col & 63)] = (OutT)acc[mi][ni][r];
        } else {  // V^T: Vt[b][h][d][s], row=h*64+d, col=b*2048+s (coalesced in s)
          C[(size_t)(col >> 11) * 2097152 + (size_t)(row >> 6) * 131072 +
            (size_t)(row & 63) * 2048 + (col & 2047)] = (OutT)acc[mi][ni][r];
        }
      }
}

// Flash attention, S^T formulation (P never touches LDS), 32x32 MFMA form.
// Qh,Kh: [B,H,S,dk]; Vt: [B,H,dk,S]; O: [B,S,H*dk]  (all bf16)
// grid: (64 b*h, 16 q-tiles); block 256 (4 waves x 32 q-rows).
// Round-10: static-named LDS double-buffer pipeline (provable NoAlias ->
// prefetch rides over compute; 142us -> 108us).
// Round-13 (VALU cut; kernel is issue-bound: Mfma 28 + VALU 62 = 90%):
//  - max tree via v_max3_f32: 31 -> 17 ops per chunk.
//  - psum via v_pk_add_f32 in an explicit pairwise tree: 32 serial scalar
//    adds (unreorderable fp chain) -> 16 packed adds, depth ~6. Legal: we
//    pick the summation order ourselves.
// Both QK^T and PV use full-rate mfma_f32_32x32x16_bf16. S^T = K*Q^T: C col =
// q = lane&31 -> ONE q per lane, softmax stats lane-local. P(f32) -> PV
// A-fragment via v_cvt_pk_bf16_f32 + v_permlane32_swap_b32 (T12, verified).
// Defer-max (THR=8 log2); l_run per-hi partial, reduced in epilogue.
__global__ __launch_bounds__(256) void attn_kernel(const __bf16* __restrict__ Qh,
                                                   const __bf16* __restrict__ Kh,
                                                   const __bf16* __restrict__ Vt,
                                                   __bf16* __restrict__ O) {
  __shared__ __bf16 Ks0[64 * 64];   // [kv][d], XOR-swizzled 16B blocks
  __shared__ __bf16 Ks1[64 * 64];
  __shared__ __bf16 Vts0[64 * 64];  // [d][kv], XOR-swizzled 16B blocks
  __shared__ __bf16 Vts1[64 * 64];

  const int tid = threadIdx.x;
  const int wave = tid >> 6, lane = tid & 63;
  const int l31 = lane & 31, hi = lane >> 5;
  const int qt = blockIdx.y, y = blockIdx.x;  // y = b*16+h
  const size_t hb = (size_t)y * 131072;
  const __bf16* Qb = Qh + hb + (size_t)qt * 128 * 64;
  const __bf16* Kb = Kh + hb;
  const __bf16* Vb = Vt + hb;
  const int wq0 = wave * 32;

  // staging geometry (per 64-kv chunk): 512 16B-slots each for K and Vt,
  // 256 threads -> 2 slots per thread per array.
  const int s0 = tid, s1 = 256 + tid;
  const int kr0 = s0 >> 3, kc0 = s0 & 7;   // K: row=kv, 8 d-blocks
  const int kr1 = s1 >> 3, kc1 = s1 & 7;
  // loop-invariant staging source base pointers (chunk c: K +c*4096, Vt +c*64)
  const __bf16* kSrc0 = Kb + (size_t)kr0 * 64 + (kc0 ^ (kr0 & 7)) * 8;
  const __bf16* kSrc1 = Kb + (size_t)kr1 * 64 + (kc1 ^ (kr1 & 7)) * 8;
  const __bf16* vSrc0 = Vb + (size_t)kr0 * 2048 + (kc0 ^ (kr0 & 7)) * 8;
  const __bf16* vSrc1 = Vb + (size_t)kr1 * 2048 + (kc1 ^ (kr1 & 7)) * 8;

  // Q fragments (B-operand of 32x32x16: col=q=lane&31, k=d=hi*8+j),
  // pre-scaled by 0.125*log2(e). 4 d-ksteps of 16.
  const float qscale = 0.125f * 1.44269504f;
  bf16x8v qf[4];
#pragma unroll
  for (int ks = 0; ks < 4; ks++) {
    bf16x8v q = *(const bf16x8v*)&Qb[(wq0 + l31) * 64 + ks * 16 + hi * 8];
#pragma unroll
    for (int j = 0; j < 8; j++) q[j] = (__bf16)((float)q[j] * qscale);
    qf[ks] = q;
  }

  // softmax state for q = wq0 + l31 (lane-local; l_run is a per-hi PARTIAL sum)
  float m_run = -INFINITY;
  float l_run = 0.f;
  f32x16 oacc[2];  // [d-tile]; col=d=nd*32+l31, row(reg)=(reg&3)+8*(reg>>2)+4*hi
#pragma unroll
  for (int nd = 0; nd < 2; nd++)
#pragma unroll
    for (int r = 0; r < 16; r++) oacc[nd][r] = 0.f;

  auto STAGE = [&](int c, __bf16* Kd, __bf16* Vd) {
    async_copy16(&Kd[s0 * 8], kSrc0 + (size_t)c * 4096);
    async_copy16(&Kd[s1 * 8], kSrc1 + (size_t)c * 4096);
    async_copy16(&Vd[s0 * 8], vSrc0 + (size_t)c * 64);
    async_copy16(&Vd[s1 * 8], vSrc1 + (size_t)c * 64);
  };

  auto COMPUTE = [&](const __bf16* Kbuf, const __bf16* Vbuf) {
    // S^T = K Q^T over 64 kv: st[kvt] (kv tile of 32), col=q=lane&31,
    // row = kvt*32 + (reg&3)+8*(reg>>2)+4*hi
    f32x16 st[2];
#pragma unroll
    for (int kvt = 0; kvt < 2; kvt++)
#pragma unroll
      for (int r = 0; r < 16; r++) st[kvt][r] = 0.f;
#pragma unroll
    for (int ks = 0; ks < 4; ks++) {
      const int sl = ((ks * 2 + hi) ^ (l31 & 7)) * 8;
      const bf16x8v kf0 = *(const bf16x8v*)&Kbuf[l31 * 64 + sl];
      const bf16x8v kf1 = *(const bf16x8v*)&Kbuf[(32 + l31) * 64 + sl];
      __builtin_amdgcn_s_setprio(1);
      st[0] = __builtin_amdgcn_mfma_f32_32x32x16_bf16(kf0, qf[ks], st[0], 0, 0, 0);
      st[1] = __builtin_amdgcn_mfma_f32_32x32x16_bf16(kf1, qf[ks], st[1], 0, 0, 0);
      __builtin_amdgcn_s_setprio(0);
    }

    // row max over own 32 st values via v_max3_f32 (17 ops, depth 4)
    float w[11];
#pragma unroll
    for (int g = 0; g < 10; g++) {
      const int i0 = 3 * g, i1 = 3 * g + 1, i2 = 3 * g + 2;
      w[g] = max3f(st[i0 >> 4][i0 & 15], st[i1 >> 4][i1 & 15], st[i2 >> 4][i2 & 15]);
    }
    w[10] = fmaxf(st[1][14], st[1][15]);
    const float x0 = max3f(w[0], w[1], w[2]);
    const float x1 = max3f(w[3], w[4], w[5]);
    const float x2 = max3f(w[6], w[7], w[8]);
    const float x3 = fmaxf(w[9], w[10]);
    float rmax = fmaxf(max3f(x0, x1, x2), x3);
    rmax = fmaxf(rmax, __shfl_xor(rmax, 32));

    // defer-max: rescale only when some q-row's max grew by >8 (log2 units).
    // First chunk: m_run=-inf -> fires -> alpha=exp2(-inf)=0, state is 0.
    if (!__all(rmax - m_run <= 8.f)) {
      const float mnew = fmaxf(m_run, rmax);
      const float alpha = __builtin_amdgcn_exp2f(m_run - mnew);
      m_run = mnew;
      l_run *= alpha;  // partial sum scales uniformly
#pragma unroll
      for (int r = 0; r < 16; r++) {
        const float ar = __shfl(alpha, (r & 3) + 8 * (r >> 2) + 4 * hi);
        oacc[0][r] *= ar;
        oacc[1][r] *= ar;
      }
    }

    // PV: exp2 on the fly; P -> bf16 A-fragments via cvt_pk + permlane32_swap.
    // l accumulated as a packed f32x2 pairwise tree (v_pk_add_f32).
    f32x2 lsum;
    lsum[0] = 0.f; lsum[1] = 0.f;
#pragma unroll
    for (int kvt = 0; kvt < 2; kvt++) {
#pragma unroll
      for (int sub = 0; sub < 2; sub++) {
        const int ks2 = kvt * 2 + sub;      // kv kstep of 16 within this chunk
        const int vs = ((ks2 * 2 + hi) ^ (l31 & 7)) * 8;
        const bf16x8v vf0 = *(const bf16x8v*)&Vbuf[l31 * 64 + vs];
        const bf16x8v vf1 = *(const bf16x8v*)&Vbuf[(32 + l31) * 64 + vs];
        const int o = sub * 8;
        float p[8];
#pragma unroll
        for (int j = 0; j < 8; j++)
          p[j] = __builtin_amdgcn_exp2f(st[kvt][o + j] - m_run);
        f32x2 a, b, c, d;
        a[0] = p[0]; a[1] = p[1]; b[0] = p[2]; b[1] = p[3];
        c[0] = p[4]; c[1] = p[5]; d[0] = p[6]; d[1] = p[7];
        lsum = pk_add(lsum, pk_add(pk_add(a, b), pk_add(c, d)));
        unsigned x0, y0, x1, y1;
        asm("v_cvt_pk_bf16_f32 %0, %1, %2" : "=v"(x0) : "v"(p[0]), "v"(p[1]));
        asm("v_cvt_pk_bf16_f32 %0, %1, %2" : "=v"(y0) : "v"(p[4]), "v"(p[5]));
        asm("v_cvt_pk_bf16_f32 %0, %1, %2" : "=v"(x1) : "v"(p[2]), "v"(p[3]));
        asm("v_cvt_pk_bf16_f32 %0, %1, %2" : "=v"(y1) : "v"(p[6]), "v"(p[7]));
        // {w0,w2} = swap(x0,y0); {w1,w3} = swap(x1,y1)
        asm("v_permlane32_swap_b32 %0, %1" : "+v"(x0), "+v"(y0));
        asm("v_permlane32_swap_b32 %0, %1" : "+v"(x1), "+v"(y1));
        union { unsigned u[4]; bf16x8v v; } af;
        af.u[0] = x0; af.u[1] = x1; af.u[2] = y0; af.u[3] = y1;
        __builtin_amdgcn_s_setprio(1);
        oacc[0] = __builtin_amdgcn_mfma_f32_32x32x16_bf16(af.v, vf0, oacc[0], 0, 0, 0);
        oacc[1] = __builtin_amdgcn_mfma_f32_32x32x16_bf16(af.v, vf1, oacc[1], 0, 0, 0);
        __builtin_amdgcn_s_setprio(0);
      }
    }
    l_run += lsum[0] + lsum[1];  // per-hi partial; reduced in epilogue
  };

  // ---- 2x-unrolled double-buffered pipeline over 32 chunks of 64 kv ----
  STAGE(0, Ks0, Vts0);
  __syncthreads();
#pragma unroll 1
  for (int t = 0; t < 15; t++) {
    STAGE(2 * t + 1, Ks1, Vts1);   // writes Ks1/Vts1: last read before prev sync
    COMPUTE(Ks0, Vts0);
    __syncthreads();               // drains prefetch (hidden under compute)
    STAGE(2 * t + 2, Ks0, Vts0);
    COMPUTE(Ks1, Vts1);
    __syncthreads();
  }
  STAGE(31, Ks1, Vts1);
  COMPUTE(Ks0, Vts0);
  __syncthreads();
  COMPUTE(Ks1, Vts1);

  // epilogue: reduce l across the 2 hi replicas, broadcast 1/l to O-rows
  l_run += __shfl_xor(l_run, 32);
  const float linv = 1.f / l_run;
  const int b = y >> 4, h = y & 15;
#pragma unroll
  for (int r = 0; r < 16; r++) {
    const int q = (r & 3) + 8 * (r >> 2) + 4 * hi;
    const float inv = __shfl(linv, q);
    const int srow = qt * 128 + wq0 + q;
    const size_t base = ((size_t)(b * 2048 + srow)) * 1024 + h * 64;
    O[base + l31] = (__bf16)(oacc[0][r] * inv);
    O[base + 32 + l31] = (__bf16)(oacc[1][r] * inv);
  }
}

extern "C" void kernel_launch(void* const* d_in, const int* in_sizes, int n_in,
                              void* d_out, int out_size, void* d_ws, size_t ws_size,
                              hipStream_t stream) {
  const float* Qin = (const float*)d_in[0];
  const float* Kin = (const float*)d_in[1];
  const float* Vin = (const float*)d_in[2];
  const float* Wq = (const float*)d_in[3];
  const float* Wk = (const float*)d_in[4];
  const float* Wv = (const float*)d_in[5];
  const float* Wo = (const float*)d_in[6];
  float* out = (float*)d_out;

  __bf16* base = (__bf16*)d_ws;
  __bf16* Qbf = base;                    // 8388608
  __bf16* Kbf = base + 8388608;
  __bf16* Vbf = base + 16777216;
  __bf16* Wqb = base + 25165824;         // 1048576 each
  __bf16* Wkb = base + 26214400;
  __bf16* Wvb = base + 27262976;
  __bf16* Wob = base + 28311552;
  __bf16* Qh = base + 29360128;          // [B,H,S,dk]
  __bf16* Kh = base + 37748736;          // [B,H,S,dk]
  __bf16* Vt = base + 46137344;          // [B,H,dk,S]
  __bf16* AO = Qbf;                      // aliases Qbf (dead after gemm1)

  CastArgs ca;
  ca.s[0] = Qin; ca.s[1] = Kin; ca.s[2] = Vin;
  ca.s[3] = Wq;  ca.s[4] = Wk;  ca.s[5] = Wv;  ca.s[6] = Wo;
  ca.d[0] = Qbf; ca.d[1] = Kbf; ca.d[2] = Vbf;
  ca.d[3] = Wqb; ca.d[4] = Wkb; ca.d[5] = Wvb; ca.d[6] = Wob;
  cast_kernel<<<dim3(4096, 7), 256, 0, stream>>>(ca);

  const int M = 8192, N = 1024, K = 1024;
  dim3 bb(512);
  // Q, K, V^T projections batched: grid (x=64, y=8, z=3).
  // z=0: Qh = Qbf*Wq^T; z=1: Kh = Kbf*Wk^T; z=2: Vt = (Wvb, Vbf) swapped-role
  // MODE-3-style write. XCD = blockIdx.x%8 keys the large operand in all z.
  gemm_bt<1, __bf16><<<dim3(64, 8, 3), bb, 0, stream>>>(
      Qbf, Wqb, Qh, Kbf, Wkb, Kh, Wvb, Vbf, Vt, M, N, K);
  attn_kernel<<<dim3(64, 16), dim3(256), 0, stream>>>(Qh, Kh, Vt, AO);
  gemm_bt<0, float><<<dim3(64, 8), bb, 0, stream>>>(
      AO, Wob, out, nullptr, nullptr, nullptr, nullptr, nullptr, nullptr,
      M, N, K);
}